// Round 15
// baseline (122.869 us; speedup 1.0000x reference)
//
#include <hip/hip_runtime.h>

// Problem constants
#define NTOK   32768
#define CDIM   128
#define NH     8
#define QT     32     // rows per k_out block

typedef __bf16 bf16;
typedef __bf16 bf16x4v __attribute__((ext_vector_type(4)));
typedef __bf16 bf16x8v __attribute__((ext_vector_type(8)));
typedef float  f32x4   __attribute__((ext_vector_type(4)));

__device__ __forceinline__ f32x4 mfma16(bf16x8v a, bf16x8v b, f32x4 c) {
  return __builtin_amdgcn_mfma_f32_16x16x32_bf16(a, b, c, 0, 0, 0);
}

// DPP 16-lane-group sum (pure VALU, off the DS pipe). HW-verified r8-r14.
template<int CTRL>
__device__ __forceinline__ float dpp_add(float x) {
  int y = __builtin_amdgcn_mov_dpp(__float_as_int(x), CTRL, 0xf, 0xf, true);
  return x + __int_as_float(y);
}
__device__ __forceinline__ float xred16d(float v) {
  v = dpp_add<0xB1>(v);    // quad_perm [1,0,3,2]
  v = dpp_add<0x4E>(v);    // quad_perm [2,3,0,1]
  v = dpp_add<0x141>(v);   // row_half_mirror
  v = dpp_add<0x140>(v);   // row_mirror
  return v;
}

// swizzled element index for row-major [R][128] bf16 LDS tiles
__device__ __forceinline__ int sidx(int row, int col) {
  return row * 128 + (col ^ ((row & 7) << 3));
}

// Fragment-tiled global layout: T[h][tile][kk][lane][8]
__device__ __forceinline__ int tidx(int h, int tile, int kk, int lane) {
  return (((h * 8 + tile) * 4 + kk) * 64 + lane) * 8;
}

// ---------------------------------------------------------------------------
// k_prepA: blocks [0,2048): source f32 -> bf16 A-fragment-tiled srcT.
//          blocks [2048,2560): Wq/Wk/Wv -> bf16 fragment-tiled (+Wvs/Wvbs).
// ---------------------------------------------------------------------------
__global__ void __launch_bounds__(256) k_prepA(
    const float* __restrict__ src,
    const float* __restrict__ Wq, const float* __restrict__ Wk,
    const float* __restrict__ Wv, const float* __restrict__ Wv_b,
    bf16* __restrict__ srcT,
    bf16* __restrict__ wqT, bf16* __restrict__ wkT, bf16* __restrict__ wvT,
    float* __restrict__ Wvs, float* __restrict__ Wvbs)
{
  const int bid = blockIdx.x;
  const int tid = threadIdx.x;
  if (bid < 2048) {
    const int rb = bid;
    const int row = tid >> 4, col0 = (tid & 15) * 8;
    const float* p = src + (rb * 16 + row) * CDIM + col0;
    f32x4 v0 = *(const f32x4*)p;
    f32x4 v1 = *(const f32x4*)(p + 4);
    bf16x8v o;
    o[0] = (bf16)v0[0]; o[1] = (bf16)v0[1]; o[2] = (bf16)v0[2]; o[3] = (bf16)v0[3];
    o[4] = (bf16)v1[0]; o[5] = (bf16)v1[1]; o[6] = (bf16)v1[2]; o[7] = (bf16)v1[3];
    const int kk = col0 >> 5, lg = (col0 >> 3) & 3;
    const int lane = row + 16 * lg;
    *(bf16x8v*)(srcT + ((rb * 4 + kk) * 64 + lane) * 8) = o;
  } else {
    const int b = bid - 2048;            // 0..511
    const int h = b >> 6;
    const int o = (b & 63) * 2 + (tid >> 7);
    const int i = tid & 127;
    const int s = (h * CDIM + o) * CDIM + i;
    const int ot = o >> 4, l15 = o & 15;
    const int kk = i >> 5, lg = (i >> 3) & 3, j = i & 7;
    const int dst = tidx(h, ot, kk, l15 + 16 * lg) + j;
    wqT[dst] = (bf16)Wq[s];
    wkT[dst] = (bf16)Wk[s];
    wvT[dst] = (bf16)Wv[s];
    if (h == 0) {
      float sm = 0.f;
#pragma unroll
      for (int hh = 0; hh < NH; ++hh) sm += Wv[(hh * CDIM + o) * CDIM + i];
      Wvs[o * CDIM + i] = sm;
      if (o == 0) {
        float sb = 0.f;
#pragma unroll
        for (int hh = 0; hh < NH; ++hh) sb += Wv_b[hh * CDIM + i];
        Wvbs[i] = sb;
      }
    }
  }
}

// ---------------------------------------------------------------------------
// k_ktv: r10-exact (XCD swizzle, hoisted weights, DPP norms, 2 barriers,
//        fragment-order partial store).  Proven: 52.9 us, no spill.
// ---------------------------------------------------------------------------
__global__ void __launch_bounds__(256, 2) k_ktv(
    const bf16* __restrict__ srcT,
    const bf16* __restrict__ wkT, const bf16* __restrict__ wvT,
    const float* __restrict__ Wk_b, const float* __restrict__ Wv_b,
    bf16* __restrict__ ktv_part, float* __restrict__ ksum_part,
    int nsub, int cpx)
{
  // XCD-locality swizzle: all 8 heads of a chunk share one XCD (bid%8).
  const int x = blockIdx.x & 7;
  const int g = blockIdx.x >> 3;
  const int c = x * cpx + (g >> 3);
  const int h = g & 7;

  const int tid = threadIdx.x;
  const int w = tid >> 6, l = tid & 63;
  const int l15 = l & 15, lg = l >> 4;
  const int os = w * 32, owt = os >> 4;

  __shared__ bf16 s_phiT[128][68];     // [m][n]  (pitch 68: 0 conflicts)
  __shared__ bf16 s_vT[128][68];       // [d][n]
  __shared__ float s_red2[8][64];      // [w*2+{a2,a4}][row] lane-coalesced
  __shared__ float s_scale[64];

  const f32x4 z4 = {0.f, 0.f, 0.f, 0.f};

  // hoisted loop-invariant weight fragments + biases (proven no-spill)
  bf16x8v bWk[2][4], bWv[2][4];
  float bK[2], bV[2];
#pragma unroll
  for (int ot = 0; ot < 2; ++ot) {
#pragma unroll
    for (int kk = 0; kk < 4; ++kk) {
      bWk[ot][kk] = *(const bf16x8v*)(wkT + tidx(h, owt + ot, kk, l));
      bWv[ot][kk] = *(const bf16x8v*)(wvT + tidx(h, owt + ot, kk, l));
    }
    bK[ot] = Wk_b[h * CDIM + os + ot * 16 + l15];
    bV[ot] = Wv_b[h * CDIM + os + ot * 16 + l15];
  }

  const int wd = (w >> 1) * 64, wm = (w & 1) * 64;
  f32x4 acc[4][4];
#pragma unroll
  for (int dt = 0; dt < 4; ++dt)
#pragma unroll
    for (int mt = 0; mt < 4; ++mt) acc[dt][mt] = z4;
  float ksacc[2] = {0.f, 0.f};

#pragma unroll 1
  for (int s = 0; s < nsub; ++s) {
    const int rbase = (c * nsub + s) * 4;   // 16-row-block index
    f32x4 accK[4][2], accV[4][2];
#pragma unroll
    for (int nt = 0; nt < 4; ++nt)
#pragma unroll
      for (int ot = 0; ot < 2; ++ot) { accK[nt][ot] = z4; accV[nt][ot] = z4; }
#pragma unroll
    for (int kk = 0; kk < 4; ++kk) {
      bf16x8v a[4];
#pragma unroll
      for (int nt = 0; nt < 4; ++nt)
        a[nt] = *(const bf16x8v*)(srcT + (((rbase + nt) * 4 + kk) * 64 + l) * 8);
#pragma unroll
      for (int nt = 0; nt < 4; ++nt)
#pragma unroll
        for (int ot = 0; ot < 2; ++ot) {
          accK[nt][ot] = mfma16(a[nt], bWk[ot][kk], accK[nt][ot]);
          accV[nt][ot] = mfma16(a[nt], bWv[ot][kk], accV[nt][ot]);
        }
    }
    bf16x4v vq[4][2];
#pragma unroll
    for (int nt = 0; nt < 4; ++nt)
#pragma unroll
      for (int ot = 0; ot < 2; ++ot)
#pragma unroll
        for (int r = 0; r < 4; ++r)
          vq[nt][ot][r] = (bf16)(accV[nt][ot][r] + bV[ot]);
#pragma unroll
    for (int nt = 0; nt < 4; ++nt)
#pragma unroll
      for (int r = 0; r < 4; ++r) {
        float a2 = 0.f, a4 = 0.f;
#pragma unroll
        for (int ot = 0; ot < 2; ++ot) {
          float xv = fmaxf(accK[nt][ot][r] + bK[ot], 0.f) + 1e-6f;
          float x2 = xv * xv;
          accK[nt][ot][r] = x2;
          a2 += x2;
          a4 += x2 * x2;
        }
        a2 = xred16d(a2);
        a4 = xred16d(a4);
        if (l15 == 0) {
          s_red2[w * 2 + 0][nt * 16 + lg * 4 + r] = a2;
          s_red2[w * 2 + 1][nt * 16 + lg * 4 + r] = a4;
        }
      }
    __syncthreads();  // B1
    {
      float S2 = s_red2[0][l] + s_red2[2][l] + s_red2[4][l] + s_red2[6][l];
      float S4 = s_red2[1][l] + s_red2[3][l] + s_red2[5][l] + s_red2[7][l];
      s_scale[l] = sqrtf(S2) / (sqrtf(S4) + 1e-8f);
    }
#pragma unroll
    for (int nt = 0; nt < 4; ++nt) {
      f32x4 sc = *(const f32x4*)&s_scale[nt * 16 + lg * 4];
#pragma unroll
      for (int ot = 0; ot < 2; ++ot) {
        bf16x4v ph;
#pragma unroll
        for (int r = 0; r < 4; ++r) {
          float p = accK[nt][ot][r] * sc[r];
          ksacc[ot] += p;
          ph[r] = (bf16)p;
        }
        const int colb = os + ot * 16 + l15;
        *(bf16x4v*)&s_phiT[colb][nt * 16 + lg * 4] = ph;
        *(bf16x4v*)&s_vT[colb][nt * 16 + lg * 4] = vq[nt][ot];
      }
    }
    __syncthreads();  // B2
#pragma unroll
    for (int kkn = 0; kkn < 2; ++kkn) {
      bf16x8v aV[4], bP[4];
#pragma unroll
      for (int dt = 0; dt < 4; ++dt)
        aV[dt] = *(const bf16x8v*)&s_vT[wd + dt * 16 + l15][kkn * 32 + lg * 8];
#pragma unroll
      for (int mt = 0; mt < 4; ++mt)
        bP[mt] = *(const bf16x8v*)&s_phiT[wm + mt * 16 + l15][kkn * 32 + lg * 8];
#pragma unroll
      for (int dt = 0; dt < 4; ++dt)
#pragma unroll
        for (int mt = 0; mt < 4; ++mt)
          acc[dt][mt] = mfma16(aV[dt], bP[mt], acc[dt][mt]);
    }
  }

#pragma unroll
  for (int ot = 0; ot < 2; ++ot) {
    ksacc[ot] += __shfl_xor(ksacc[ot], 16);
    ksacc[ot] += __shfl_xor(ksacc[ot], 32);
  }
  if (l < 16) {
#pragma unroll
    for (int ot = 0; ot < 2; ++ot)
      ksum_part[(c * NH + h) * CDIM + os + ot * 16 + l] = ksacc[ot];
  }
  bf16* kp = ktv_part + ((c * NH + h) * 4 + w) * 4096;
#pragma unroll
  for (int dt = 0; dt < 4; ++dt)
#pragma unroll
    for (int mt = 0; mt < 4; ++mt) {
      bf16x4v q;
#pragma unroll
      for (int r = 0; r < 4; ++r) q[r] = (bf16)acc[dt][mt][r];
      *(bf16x4v*)(kp + ((dt * 4 + mt) * 64 + l) * 4) = q;
    }
}

// ---------------------------------------------------------------------------
// k_finishB: r10-exact.
// ---------------------------------------------------------------------------
__global__ void __launch_bounds__(256) k_finishB(
    const bf16* __restrict__ ktv_part, const float* __restrict__ ksum_part,
    const float* __restrict__ vmw, const float* __restrict__ vmb,
    const float* __restrict__ Wvs, const float* __restrict__ Wvbs,
    bf16* __restrict__ ktvT, bf16* __restrict__ ksb,
    bf16* __restrict__ w2sT, float* __restrict__ b2s, int nchunk)
{
  const int b = blockIdx.x;
  if (b < 512) {
    const int t = b * 256 + threadIdx.x;          // < 131072
    const int h = t >> 14;
    const int rem = t & 16383;
    const int d = rem >> 7, m = rem & 127;
    const int wq = ((d >> 6) << 1) | (m >> 6);
    const int dd = d & 63, mm = m & 63;
    const int dt = dd >> 4, r = dd & 3, lgp = (dd >> 2) & 3;
    const int mt = mm >> 4, l15p = mm & 15;
    const int lane = lgp * 16 + l15p;
    const int off = (h * 4 + wq) * 4096 + ((dt * 4 + mt) * 64 + lane) * 4 + r;
    float a = 0.f;
    for (int c = 0; c < nchunk; ++c)
      a += (float)ktv_part[c * (NH * 4 * 4096) + off];
    const int dtile = d >> 4, dl15 = d & 15;
    const int kk = m >> 5, mlg = (m >> 3) & 3, j = m & 7;
    ktvT[tidx(h, dtile, kk, dl15 + 16 * mlg) + j] = (bf16)a;
  } else if (b < 576) {
    const int t = (b - 512) * 256 + threadIdx.x;  // < 16384
    const int h = t >> 11;
    const int rem = t & 2047;
    const int kk = rem >> 9, lane = (rem >> 3) & 63, j = rem & 7;
    const int l15 = lane & 15, lg = lane >> 4;
    float a = 0.f;
    if (l15 == 0) {
      const int m = 32 * kk + 8 * lg + j;
      for (int c = 0; c < nchunk; ++c) a += ksum_part[(c * NH + h) * CDIM + m];
    }
    ksb[t] = (bf16)a;
  } else {
    const int sub = threadIdx.x >> 7, i = threadIdx.x & 127;
    const int o = (b - 576) * 2 + sub;
    __shared__ float s_vm[2][128];
    __shared__ float s_rd[2][128];
    s_vm[sub][i] = vmw[o * CDIM + i];
    __syncthreads();
    float acc = 0.f;
    for (int d = 0; d < CDIM; ++d) acc = fmaf(s_vm[sub][d], Wvs[d * CDIM + i], acc);
    const int ot = o >> 4, l15 = o & 15;
    const int kk = i >> 5, lg = (i >> 3) & 3, j = i & 7;
    w2sT[tidx(0, ot, kk, l15 + 16 * lg) + j] = (bf16)acc;
    s_rd[sub][i] = s_vm[sub][i] * Wvbs[i];
    __syncthreads();
    for (int st = 64; st > 0; st >>= 1) {
      if (i < st) s_rd[sub][i] += s_rd[sub][i + st];
      __syncthreads();
    }
    if (i == 0) b2s[o] = s_rd[sub][0] + 8.f * vmb[o];
  }
}

// ---------------------------------------------------------------------------
// k_out: QT=32, SINGLE BARRIER head loop.
//   Phase 1: all 8 heads {wf load -> qs GEMM -> x2 -> s_phi[h]}  (8 buffers,
//            no reuse -> no WAR).  ONE __syncthreads().
//   Phase 2: all 8 heads {kf/kt load -> num GEMM (+T) -> divide -> accO}.
//   #pragma unroll 1 on both loops keeps transient loads from being hoisted
//   across heads (r9 spill lesson).  LDS 72.5 KB -> still 2 blocks/CU
//   (occupancy is register-capped at 2 waves/SIMD regardless).
// ---------------------------------------------------------------------------
__global__ void __launch_bounds__(256, 2) k_out(
    const float* __restrict__ query, const bf16* __restrict__ srcT,
    const bf16* __restrict__ wqT, const float* __restrict__ Wq_b,
    const bf16* __restrict__ ktvT, const bf16* __restrict__ ksb,
    const bf16* __restrict__ w2sT, const float* __restrict__ b2s,
    float* __restrict__ out)
{
  const int nb = blockIdx.x * QT;
  const int tid = threadIdx.x;
  const int w = tid >> 6, l = tid & 63;
  const int l15 = l & 15, lg = l >> 4;
  const int os = w * 32, owt = os >> 4;

  __shared__ bf16 s_q[QT * 128];        // XOR-swizzled
  __shared__ bf16 s_phi[NH][QT * 128];  // one buffer per head
  __shared__ float s_time[4][QT] __attribute__((aligned(16)));

  const f32x4 z4 = {0.f, 0.f, 0.f, 0.f};

#pragma unroll
  for (int j = 0; j < 4; ++j) {
    const int flat = tid + j * 256;
    const int n = flat >> 5, c4 = (flat & 31) * 4;
    f32x4 vq = *(const f32x4*)(query + (nb + n) * CDIM + c4);
    bf16x4v bq;
    bq[0] = (bf16)vq[0]; bq[1] = (bf16)vq[1]; bq[2] = (bf16)vq[2]; bq[3] = (bf16)vq[3];
    *(bf16x4v*)&s_q[sidx(n, c4)] = bq;
  }

  f32x4 accO[2][2];
#pragma unroll
  for (int nt = 0; nt < 2; ++nt)
#pragma unroll
    for (int ot = 0; ot < 2; ++ot) accO[nt][ot] = z4;

  __syncthreads();

  bf16x8v aq[2][4];
#pragma unroll
  for (int nt = 0; nt < 2; ++nt)
#pragma unroll
    for (int kk = 0; kk < 4; ++kk)
      aq[nt][kk] = *(const bf16x8v*)&s_q[sidx(nt * 16 + l15, kk * 32 + lg * 8)];

  // ---- phase 1: all qs GEMMs -> x2 packs
#pragma unroll 1
  for (int h = 0; h < NH; ++h) {
    bf16x8v wf[2][4];
#pragma unroll
    for (int ot = 0; ot < 2; ++ot)
#pragma unroll
      for (int kk = 0; kk < 4; ++kk)
        wf[ot][kk] = *(const bf16x8v*)(wqT + tidx(h, owt + ot, kk, l));
    float bQ[2];
#pragma unroll
    for (int ot = 0; ot < 2; ++ot) bQ[ot] = Wq_b[h * CDIM + os + ot * 16 + l15];

    f32x4 accQ[2][2];
#pragma unroll
    for (int nt = 0; nt < 2; ++nt)
#pragma unroll
      for (int ot = 0; ot < 2; ++ot) accQ[nt][ot] = z4;
#pragma unroll
    for (int kk = 0; kk < 4; ++kk)
#pragma unroll
      for (int ot = 0; ot < 2; ++ot)
#pragma unroll
        for (int nt = 0; nt < 2; ++nt)
          accQ[nt][ot] = mfma16(aq[nt][kk], wf[ot][kk], accQ[nt][ot]);

    bf16* ph = s_phi[h];
#pragma unroll
    for (int nt = 0; nt < 2; ++nt)
#pragma unroll
      for (int ot = 0; ot < 2; ++ot)
#pragma unroll
        for (int r = 0; r < 4; ++r) {
          float xv = fmaxf(accQ[nt][ot][r] + bQ[ot], 0.f) + 1e-6f;
          ph[sidx(nt * 16 + lg * 4 + r, os + ot * 16 + l15)] = (bf16)(xv * xv);
        }
  }
  __syncthreads();   // THE single barrier of the head path

  // ---- phase 2: all num GEMMs
#pragma unroll 1
  for (int h = 0; h < NH; ++h) {
    bf16x8v kf[2][4], kt[4];
#pragma unroll
    for (int ot = 0; ot < 2; ++ot)
#pragma unroll
      for (int kk = 0; kk < 4; ++kk)
        kf[ot][kk] = *(const bf16x8v*)(ktvT + tidx(h, owt + ot, kk, l));
#pragma unroll
    for (int kk = 0; kk < 4; ++kk)
      kt[kk] = *(const bf16x8v*)(ksb + ((h * 4 + kk) * 64 + l) * 8);

    const bf16* ph = s_phi[h];
    bf16x8v ap[2][4];
#pragma unroll
    for (int nt = 0; nt < 2; ++nt)
#pragma unroll
      for (int kk = 0; kk < 4; ++kk)
        ap[nt][kk] = *(const bf16x8v*)&ph[sidx(nt * 16 + l15, kk * 32 + lg * 8)];

    f32x4 accN[2][2], accT[2];
#pragma unroll
    for (int nt = 0; nt < 2; ++nt) {
      accT[nt] = z4;
#pragma unroll
      for (int dt = 0; dt < 2; ++dt) accN[nt][dt] = z4;
    }
#pragma unroll
    for (int kk = 0; kk < 4; ++kk) {
#pragma unroll
      for (int dt = 0; dt < 2; ++dt)
#pragma unroll
        for (int nt = 0; nt < 2; ++nt)
          accN[nt][dt] = mfma16(ap[nt][kk], kf[dt][kk], accN[nt][dt]);
#pragma unroll
      for (int nt = 0; nt < 2; ++nt)
        accT[nt] = mfma16(ap[nt][kk], kt[kk], accT[nt]);
    }
#pragma unroll
    for (int nt = 0; nt < 2; ++nt)
#pragma unroll
      for (int r = 0; r < 4; ++r) {
        float tr = __shfl(accT[nt][r], l & 48);
        float m = 1.0f / tr;
#pragma unroll
        for (int dt = 0; dt < 2; ++dt)
          accO[nt][dt][r] = fmaf(accN[nt][dt][r], m, accO[nt][dt][r]);
      }
  }

  // fused vss GEMM: A-frags from srcT
  const int rb0 = blockIdx.x * 2;
#pragma unroll
  for (int kk = 0; kk < 4; ++kk) {
    bf16x8v a[2];
#pragma unroll
    for (int nt = 0; nt < 2; ++nt)
      a[nt] = *(const bf16x8v*)(srcT + (((rb0 + nt) * 4 + kk) * 64 + l) * 8);
#pragma unroll
    for (int ot = 0; ot < 2; ++ot) {
      bf16x8v bw = *(const bf16x8v*)(w2sT + tidx(0, owt + ot, kk, l));
#pragma unroll
      for (int nt = 0; nt < 2; ++nt)
        accO[nt][ot] = mfma16(a[nt], bw, accO[nt][ot]);
    }
  }
  float bb[2];
#pragma unroll
  for (int ot = 0; ot < 2; ++ot) bb[ot] = b2s[os + ot * 16 + l15];

  float ps[2][4];
#pragma unroll
  for (int nt = 0; nt < 2; ++nt)
#pragma unroll
    for (int r = 0; r < 4; ++r) ps[nt][r] = 0.f;
#pragma unroll
  for (int nt = 0; nt < 2; ++nt)
#pragma unroll
    for (int ot = 0; ot < 2; ++ot)
#pragma unroll
      for (int r = 0; r < 4; ++r) {
        float v = (accO[nt][ot][r] + bb[ot]) * 0.125f;
        accO[nt][ot][r] = v;
        ps[nt][r] += v * v;
      }
#pragma unroll
  for (int nt = 0; nt < 2; ++nt)
#pragma unroll
    for (int r = 0; r < 4; ++r) {
      float t = xred16d(ps[nt][r]);
      if (l15 == 0) s_time[w][nt * 16 + lg * 4 + r] = t;
    }
#pragma unroll
  for (int nt = 0; nt < 2; ++nt)
#pragma unroll
    for (int ot = 0; ot < 2; ++ot)
#pragma unroll
      for (int r = 0; r < 4; ++r)
        out[(nb + nt * 16 + lg * 4 + r) * 129 + 1 + os + ot * 16 + l15] = accO[nt][ot][r];
  __syncthreads();
  if (tid < QT) {
    float S = 1.0f + s_time[0][tid] + s_time[1][tid] + s_time[2][tid] + s_time[3][tid];
    out[(nb + tid) * 129] = sqrtf(S);
  }
}

// ---------------------------------------------------------------------------
extern "C" void kernel_launch(void* const* d_in, const int* in_sizes, int n_in,
                              void* d_out, int out_size, void* d_ws, size_t ws_size,
                              hipStream_t stream) {
  const float* query  = (const float*)d_in[0];
  const float* source = (const float*)d_in[1];
  const float* Wq_w   = (const float*)d_in[2];
  const float* Wq_b   = (const float*)d_in[3];
  const float* Wk_w   = (const float*)d_in[4];
  const float* Wk_b   = (const float*)d_in[5];
  const float* Wv_w   = (const float*)d_in[6];
  const float* Wv_b   = (const float*)d_in[7];
  const float* vmw    = (const float*)d_in[8];
  const float* vmb    = (const float*)d_in[9];

  char* ws = (char*)d_ws;
  bf16*  wqT       = (bf16*)(ws + 0);           // 262144
  bf16*  wkT       = (bf16*)(ws + 262144);      // 262144
  bf16*  wvT       = (bf16*)(ws + 524288);      // 262144
  bf16*  w2sT      = (bf16*)(ws + 786432);      // 32768
  float* b2s       = (float*)(ws + 819200);     // 512
  float* Wvs       = (float*)(ws + 819712);     // 65536
  float* Wvbs      = (float*)(ws + 885248);     // 512
  bf16*  ktvT      = (bf16*)(ws + 885760);      // 262144
  bf16*  ksb       = (bf16*)(ws + 1147904);     // 32768
  bf16*  srcT      = (bf16*)(ws + 1180672);     // 8388608
  float* ksum_part = (float*)(ws + 9569280);    // 262144
  bf16*  ktv_part  = (bf16*)(ws + 10093568);    // 64*262144 = 16.78 MB

  int nchunk = 64, nsub = 8;
  if (ws_size < 10093568ull + 64ull * 262144ull) { nchunk = 32; nsub = 16; }

  k_prepA<<<2560, 256, 0, stream>>>(source, Wq_w, Wk_w, Wv_w, Wv_b,
                                    srcT, wqT, wkT, wvT, Wvs, Wvbs);
  k_ktv<<<nchunk * NH, 256, 0, stream>>>(srcT, wkT, wvT, Wk_b, Wv_b,
                                         ktv_part, ksum_part, nsub, nchunk / 8);
  k_finishB<<<640, 256, 0, stream>>>(ktv_part, ksum_part, vmw, vmb, Wvs, Wvbs,
                                     ktvT, ksb, w2sT, b2s, nchunk);
  k_out<<<NTOK / QT, 256, 0, stream>>>(query, srcT, wqT, Wq_b, ktvT, ksb,
                                       w2sT, b2s, (float*)d_out);
}

// Round 16
// 108.231 us; speedup vs baseline: 1.1353x; 1.1353x over previous
//
#include <hip/hip_runtime.h>

// Problem constants
#define NTOK   32768
#define CDIM   128
#define NH     8
#define QT     32     // rows per k_out block

typedef __bf16 bf16;
typedef __bf16 bf16x4v __attribute__((ext_vector_type(4)));
typedef __bf16 bf16x8v __attribute__((ext_vector_type(8)));
typedef float  f32x4   __attribute__((ext_vector_type(4)));

__device__ __forceinline__ f32x4 mfma16(bf16x8v a, bf16x8v b, f32x4 c) {
  return __builtin_amdgcn_mfma_f32_16x16x32_bf16(a, b, c, 0, 0, 0);
}

// DPP 16-lane-group sum (pure VALU, off the DS pipe). HW-verified r8-r15.
template<int CTRL>
__device__ __forceinline__ float dpp_add(float x) {
  int y = __builtin_amdgcn_mov_dpp(__float_as_int(x), CTRL, 0xf, 0xf, true);
  return x + __int_as_float(y);
}
__device__ __forceinline__ float xred16d(float v) {
  v = dpp_add<0xB1>(v);    // quad_perm [1,0,3,2]
  v = dpp_add<0x4E>(v);    // quad_perm [2,3,0,1]
  v = dpp_add<0x141>(v);   // row_half_mirror
  v = dpp_add<0x140>(v);   // row_mirror
  return v;
}

// swizzled element index for row-major [R][128] bf16 LDS tiles
__device__ __forceinline__ int sidx(int row, int col) {
  return row * 128 + (col ^ ((row & 7) << 3));
}

// Fragment-tiled global layout: T[h][tile][kk][lane][8]
__device__ __forceinline__ int tidx(int h, int tile, int kk, int lane) {
  return (((h * 8 + tile) * 4 + kk) * 64 + lane) * 8;
}

// ---------------------------------------------------------------------------
// k_prepA: blocks [0,2048): source f32 -> bf16 A-fragment-tiled srcT.
//          blocks [2048,2560): Wq/Wk/Wv -> bf16 fragment-tiled (+Wvs/Wvbs).
// ---------------------------------------------------------------------------
__global__ void __launch_bounds__(256) k_prepA(
    const float* __restrict__ src,
    const float* __restrict__ Wq, const float* __restrict__ Wk,
    const float* __restrict__ Wv, const float* __restrict__ Wv_b,
    bf16* __restrict__ srcT,
    bf16* __restrict__ wqT, bf16* __restrict__ wkT, bf16* __restrict__ wvT,
    float* __restrict__ Wvs, float* __restrict__ Wvbs)
{
  const int bid = blockIdx.x;
  const int tid = threadIdx.x;
  if (bid < 2048) {
    const int rb = bid;
    const int row = tid >> 4, col0 = (tid & 15) * 8;
    const float* p = src + (rb * 16 + row) * CDIM + col0;
    f32x4 v0 = *(const f32x4*)p;
    f32x4 v1 = *(const f32x4*)(p + 4);
    bf16x8v o;
    o[0] = (bf16)v0[0]; o[1] = (bf16)v0[1]; o[2] = (bf16)v0[2]; o[3] = (bf16)v0[3];
    o[4] = (bf16)v1[0]; o[5] = (bf16)v1[1]; o[6] = (bf16)v1[2]; o[7] = (bf16)v1[3];
    const int kk = col0 >> 5, lg = (col0 >> 3) & 3;
    const int lane = row + 16 * lg;
    *(bf16x8v*)(srcT + ((rb * 4 + kk) * 64 + lane) * 8) = o;
  } else {
    const int b = bid - 2048;            // 0..511
    const int h = b >> 6;
    const int o = (b & 63) * 2 + (tid >> 7);
    const int i = tid & 127;
    const int s = (h * CDIM + o) * CDIM + i;
    const int ot = o >> 4, l15 = o & 15;
    const int kk = i >> 5, lg = (i >> 3) & 3, j = i & 7;
    const int dst = tidx(h, ot, kk, l15 + 16 * lg) + j;
    wqT[dst] = (bf16)Wq[s];
    wkT[dst] = (bf16)Wk[s];
    wvT[dst] = (bf16)Wv[s];
    if (h == 0) {
      float sm = 0.f;
#pragma unroll
      for (int hh = 0; hh < NH; ++hh) sm += Wv[(hh * CDIM + o) * CDIM + i];
      Wvs[o * CDIM + i] = sm;
      if (o == 0) {
        float sb = 0.f;
#pragma unroll
        for (int hh = 0; hh < NH; ++hh) sb += Wv_b[hh * CDIM + i];
        Wvbs[i] = sb;
      }
    }
  }
}

// ---------------------------------------------------------------------------
// k_ktv: r10 structure + EARLY V-PACK into double-buffered s_vT (v doesn't
//        depend on norms; opposite buffer -> race-free, shortens B1->B2) +
//        s_setprio around the ktv MFMA cluster (2 independent blocks/CU at
//        staggered phases -> scheduler can prefer MFMA wave).
// ---------------------------------------------------------------------------
__global__ void __launch_bounds__(256, 2) k_ktv(
    const bf16* __restrict__ srcT,
    const bf16* __restrict__ wkT, const bf16* __restrict__ wvT,
    const float* __restrict__ Wk_b, const float* __restrict__ Wv_b,
    bf16* __restrict__ ktv_part, float* __restrict__ ksum_part,
    int nsub, int cpx)
{
  // XCD-locality swizzle: all 8 heads of a chunk share one XCD (bid%8).
  const int x = blockIdx.x & 7;
  const int g = blockIdx.x >> 3;
  const int c = x * cpx + (g >> 3);
  const int h = g & 7;

  const int tid = threadIdx.x;
  const int w = tid >> 6, l = tid & 63;
  const int l15 = l & 15, lg = l >> 4;
  const int os = w * 32, owt = os >> 4;

  __shared__ bf16 s_phiT[128][68];     // [m][n]  (pitch 68: 0 conflicts)
  __shared__ bf16 s_vT[2][128][68];    // [buf][d][n] double-buffered
  __shared__ float s_red2[8][64];      // [w*2+{a2,a4}][row]
  __shared__ float s_scale[64];

  const f32x4 z4 = {0.f, 0.f, 0.f, 0.f};

  // hoisted loop-invariant weight fragments + biases (proven no-spill)
  bf16x8v bWk[2][4], bWv[2][4];
  float bK[2], bV[2];
#pragma unroll
  for (int ot = 0; ot < 2; ++ot) {
#pragma unroll
    for (int kk = 0; kk < 4; ++kk) {
      bWk[ot][kk] = *(const bf16x8v*)(wkT + tidx(h, owt + ot, kk, l));
      bWv[ot][kk] = *(const bf16x8v*)(wvT + tidx(h, owt + ot, kk, l));
    }
    bK[ot] = Wk_b[h * CDIM + os + ot * 16 + l15];
    bV[ot] = Wv_b[h * CDIM + os + ot * 16 + l15];
  }

  const int wd = (w >> 1) * 64, wm = (w & 1) * 64;
  f32x4 acc[4][4];
#pragma unroll
  for (int dt = 0; dt < 4; ++dt)
#pragma unroll
    for (int mt = 0; mt < 4; ++mt) acc[dt][mt] = z4;
  float ksacc[2] = {0.f, 0.f};

#pragma unroll 1
  for (int s = 0; s < nsub; ++s) {
    const int rbase = (c * nsub + s) * 4;
    const int vb = s & 1;
    // proj GEMMs
    f32x4 accK[4][2], accV[4][2];
#pragma unroll
    for (int nt = 0; nt < 4; ++nt)
#pragma unroll
      for (int ot = 0; ot < 2; ++ot) { accK[nt][ot] = z4; accV[nt][ot] = z4; }
#pragma unroll
    for (int kk = 0; kk < 4; ++kk) {
      bf16x8v a[4];
#pragma unroll
      for (int nt = 0; nt < 4; ++nt)
        a[nt] = *(const bf16x8v*)(srcT + (((rbase + nt) * 4 + kk) * 64 + l) * 8);
#pragma unroll
      for (int nt = 0; nt < 4; ++nt)
#pragma unroll
        for (int ot = 0; ot < 2; ++ot) {
          accK[nt][ot] = mfma16(a[nt], bWk[ot][kk], accK[nt][ot]);
          accV[nt][ot] = mfma16(a[nt], bWv[ot][kk], accV[nt][ot]);
        }
    }
    // EARLY v-pack -> s_vT[vb] (prev MFMA reads s_vT[vb^1]; no barrier needed)
#pragma unroll
    for (int nt = 0; nt < 4; ++nt)
#pragma unroll
      for (int ot = 0; ot < 2; ++ot) {
        bf16x4v vv;
#pragma unroll
        for (int r = 0; r < 4; ++r)
          vv[r] = (bf16)(accV[nt][ot][r] + bV[ot]);
        *(bf16x4v*)&s_vT[vb][os + ot * 16 + l15][nt * 16 + lg * 4] = vv;
      }
    // x^2 + strip norms via DPP
#pragma unroll
    for (int nt = 0; nt < 4; ++nt)
#pragma unroll
      for (int r = 0; r < 4; ++r) {
        float a2 = 0.f, a4 = 0.f;
#pragma unroll
        for (int ot = 0; ot < 2; ++ot) {
          float xv = fmaxf(accK[nt][ot][r] + bK[ot], 0.f) + 1e-6f;
          float x2 = xv * xv;
          accK[nt][ot][r] = x2;
          a2 += x2;
          a4 += x2 * x2;
        }
        a2 = xred16d(a2);
        a4 = xred16d(a4);
        if (l15 == 0) {
          s_red2[w * 2 + 0][nt * 16 + lg * 4 + r] = a2;
          s_red2[w * 2 + 1][nt * 16 + lg * 4 + r] = a4;
        }
      }
    __syncthreads();  // B1
    {
      float S2 = s_red2[0][l] + s_red2[2][l] + s_red2[4][l] + s_red2[6][l];
      float S4 = s_red2[1][l] + s_red2[3][l] + s_red2[5][l] + s_red2[7][l];
      s_scale[l] = sqrtf(S2) / (sqrtf(S4) + 1e-8f);
    }
    // pack phi only (v already in LDS)
#pragma unroll
    for (int nt = 0; nt < 4; ++nt) {
      f32x4 sc = *(const f32x4*)&s_scale[nt * 16 + lg * 4];
#pragma unroll
      for (int ot = 0; ot < 2; ++ot) {
        bf16x4v ph;
#pragma unroll
        for (int r = 0; r < 4; ++r) {
          float p = accK[nt][ot][r] * sc[r];
          ksacc[ot] += p;
          ph[r] = (bf16)p;
        }
        *(bf16x4v*)&s_phiT[os + ot * 16 + l15][nt * 16 + lg * 4] = ph;
      }
    }
    __syncthreads();  // B2
    // ktv += v^T phi (wave quadrant 64x64)
    __builtin_amdgcn_s_setprio(1);
#pragma unroll
    for (int kkn = 0; kkn < 2; ++kkn) {
      bf16x8v aV[4], bP[4];
#pragma unroll
      for (int dt = 0; dt < 4; ++dt)
        aV[dt] = *(const bf16x8v*)&s_vT[vb][wd + dt * 16 + l15][kkn * 32 + lg * 8];
#pragma unroll
      for (int mt = 0; mt < 4; ++mt)
        bP[mt] = *(const bf16x8v*)&s_phiT[wm + mt * 16 + l15][kkn * 32 + lg * 8];
#pragma unroll
      for (int dt = 0; dt < 4; ++dt)
#pragma unroll
        for (int mt = 0; mt < 4; ++mt)
          acc[dt][mt] = mfma16(aV[dt], bP[mt], acc[dt][mt]);
    }
    __builtin_amdgcn_s_setprio(0);
  }

#pragma unroll
  for (int ot = 0; ot < 2; ++ot) {
    ksacc[ot] += __shfl_xor(ksacc[ot], 16);
    ksacc[ot] += __shfl_xor(ksacc[ot], 32);
  }
  if (l < 16) {
#pragma unroll
    for (int ot = 0; ot < 2; ++ot)
      ksum_part[(c * NH + h) * CDIM + os + ot * 16 + l] = ksacc[ot];
  }
  bf16* kp = ktv_part + ((c * NH + h) * 4 + w) * 4096;
#pragma unroll
  for (int dt = 0; dt < 4; ++dt)
#pragma unroll
    for (int mt = 0; mt < 4; ++mt) {
      bf16x4v q;
#pragma unroll
      for (int r = 0; r < 4; ++r) q[r] = (bf16)acc[dt][mt][r];
      *(bf16x4v*)(kp + ((dt * 4 + mt) * 64 + l) * 4) = q;
    }
}

// ---------------------------------------------------------------------------
// k_finishB: r10-exact.
// ---------------------------------------------------------------------------
__global__ void __launch_bounds__(256) k_finishB(
    const bf16* __restrict__ ktv_part, const float* __restrict__ ksum_part,
    const float* __restrict__ vmw, const float* __restrict__ vmb,
    const float* __restrict__ Wvs, const float* __restrict__ Wvbs,
    bf16* __restrict__ ktvT, bf16* __restrict__ ksb,
    bf16* __restrict__ w2sT, float* __restrict__ b2s, int nchunk)
{
  const int b = blockIdx.x;
  if (b < 512) {
    const int t = b * 256 + threadIdx.x;          // < 131072
    const int h = t >> 14;
    const int rem = t & 16383;
    const int d = rem >> 7, m = rem & 127;
    const int wq = ((d >> 6) << 1) | (m >> 6);
    const int dd = d & 63, mm = m & 63;
    const int dt = dd >> 4, r = dd & 3, lgp = (dd >> 2) & 3;
    const int mt = mm >> 4, l15p = mm & 15;
    const int lane = lgp * 16 + l15p;
    const int off = (h * 4 + wq) * 4096 + ((dt * 4 + mt) * 64 + lane) * 4 + r;
    float a = 0.f;
    for (int c = 0; c < nchunk; ++c)
      a += (float)ktv_part[c * (NH * 4 * 4096) + off];
    const int dtile = d >> 4, dl15 = d & 15;
    const int kk = m >> 5, mlg = (m >> 3) & 3, j = m & 7;
    ktvT[tidx(h, dtile, kk, dl15 + 16 * mlg) + j] = (bf16)a;
  } else if (b < 576) {
    const int t = (b - 512) * 256 + threadIdx.x;  // < 16384
    const int h = t >> 11;
    const int rem = t & 2047;
    const int kk = rem >> 9, lane = (rem >> 3) & 63, j = rem & 7;
    const int l15 = lane & 15, lg = lane >> 4;
    float a = 0.f;
    if (l15 == 0) {
      const int m = 32 * kk + 8 * lg + j;
      for (int c = 0; c < nchunk; ++c) a += ksum_part[(c * NH + h) * CDIM + m];
    }
    ksb[t] = (bf16)a;
  } else {
    const int sub = threadIdx.x >> 7, i = threadIdx.x & 127;
    const int o = (b - 576) * 2 + sub;
    __shared__ float s_vm[2][128];
    __shared__ float s_rd[2][128];
    s_vm[sub][i] = vmw[o * CDIM + i];
    __syncthreads();
    float acc = 0.f;
    for (int d = 0; d < CDIM; ++d) acc = fmaf(s_vm[sub][d], Wvs[d * CDIM + i], acc);
    const int ot = o >> 4, l15 = o & 15;
    const int kk = i >> 5, lg = (i >> 3) & 3, j = i & 7;
    w2sT[tidx(0, ot, kk, l15 + 16 * lg) + j] = (bf16)acc;
    s_rd[sub][i] = s_vm[sub][i] * Wvbs[i];
    __syncthreads();
    for (int st = 64; st > 0; st >>= 1) {
      if (i < st) s_rd[sub][i] += s_rd[sub][i + st];
      __syncthreads();
    }
    if (i == 0) b2s[o] = s_rd[sub][0] + 8.f * vmb[o];
  }
}

// ---------------------------------------------------------------------------
// k_out: r14-exact (two heads per iteration, 4 barriers) + setprio around
//        the num-GEMM MFMA clusters.
// ---------------------------------------------------------------------------
__global__ void __launch_bounds__(256, 2) k_out(
    const float* __restrict__ query, const bf16* __restrict__ srcT,
    const bf16* __restrict__ wqT, const float* __restrict__ Wq_b,
    const bf16* __restrict__ ktvT, const bf16* __restrict__ ksb,
    const bf16* __restrict__ w2sT, const float* __restrict__ b2s,
    float* __restrict__ out)
{
  const int nb = blockIdx.x * QT;
  const int tid = threadIdx.x;
  const int w = tid >> 6, l = tid & 63;
  const int l15 = l & 15, lg = l >> 4;
  const int os = w * 32, owt = os >> 4;

  __shared__ bf16 s_q[QT * 128];          // XOR-swizzled
  __shared__ bf16 s_phi[2][2][QT * 128];  // [pair&1][head-in-pair]
  __shared__ float s_time[4][QT] __attribute__((aligned(16)));

  const f32x4 z4 = {0.f, 0.f, 0.f, 0.f};

#pragma unroll
  for (int j = 0; j < 4; ++j) {
    const int flat = tid + j * 256;
    const int n = flat >> 5, c4 = (flat & 31) * 4;
    f32x4 vq = *(const f32x4*)(query + (nb + n) * CDIM + c4);
    bf16x4v bq;
    bq[0] = (bf16)vq[0]; bq[1] = (bf16)vq[1]; bq[2] = (bf16)vq[2]; bq[3] = (bf16)vq[3];
    *(bf16x4v*)&s_q[sidx(n, c4)] = bq;
  }

  f32x4 accO[2][2];
#pragma unroll
  for (int nt = 0; nt < 2; ++nt)
#pragma unroll
    for (int ot = 0; ot < 2; ++ot) accO[nt][ot] = z4;

  __syncthreads();

  bf16x8v aq[2][4];
#pragma unroll
  for (int nt = 0; nt < 2; ++nt)
#pragma unroll
    for (int kk = 0; kk < 4; ++kk)
      aq[nt][kk] = *(const bf16x8v*)&s_q[sidx(nt * 16 + l15, kk * 32 + lg * 8)];

#pragma unroll 1
  for (int hp = 0; hp < 4; ++hp) {
    const int h0 = hp * 2, h1 = h0 + 1;
    const int pb = hp & 1;
    bf16x8v wf0[2][4], wf1[2][4], kf0[2][4], kt0[4];
#pragma unroll
    for (int ot = 0; ot < 2; ++ot)
#pragma unroll
      for (int kk = 0; kk < 4; ++kk) {
        wf0[ot][kk] = *(const bf16x8v*)(wqT + tidx(h0, owt + ot, kk, l));
        wf1[ot][kk] = *(const bf16x8v*)(wqT + tidx(h1, owt + ot, kk, l));
        kf0[ot][kk] = *(const bf16x8v*)(ktvT + tidx(h0, owt + ot, kk, l));
      }
#pragma unroll
    for (int kk = 0; kk < 4; ++kk)
      kt0[kk] = *(const bf16x8v*)(ksb + ((h0 * 4 + kk) * 64 + l) * 8);
    float bQ0[2], bQ1[2];
#pragma unroll
    for (int ot = 0; ot < 2; ++ot) {
      bQ0[ot] = Wq_b[h0 * CDIM + os + ot * 16 + l15];
      bQ1[ot] = Wq_b[h1 * CDIM + os + ot * 16 + l15];
    }

    f32x4 accQ0[2][2], accQ1[2][2];
#pragma unroll
    for (int nt = 0; nt < 2; ++nt)
#pragma unroll
      for (int ot = 0; ot < 2; ++ot) { accQ0[nt][ot] = z4; accQ1[nt][ot] = z4; }
#pragma unroll
    for (int kk = 0; kk < 4; ++kk)
#pragma unroll
      for (int ot = 0; ot < 2; ++ot)
#pragma unroll
        for (int nt = 0; nt < 2; ++nt) {
          accQ0[nt][ot] = mfma16(aq[nt][kk], wf0[ot][kk], accQ0[nt][ot]);
          accQ1[nt][ot] = mfma16(aq[nt][kk], wf1[ot][kk], accQ1[nt][ot]);
        }

    bf16* ph0 = s_phi[pb][0];
    bf16* ph1 = s_phi[pb][1];
#pragma unroll
    for (int nt = 0; nt < 2; ++nt)
#pragma unroll
      for (int ot = 0; ot < 2; ++ot)
#pragma unroll
        for (int r = 0; r < 4; ++r) {
          const int ro = sidx(nt * 16 + lg * 4 + r, os + ot * 16 + l15);
          float x0 = fmaxf(accQ0[nt][ot][r] + bQ0[ot], 0.f) + 1e-6f;
          float x1 = fmaxf(accQ1[nt][ot][r] + bQ1[ot], 0.f) + 1e-6f;
          ph0[ro] = (bf16)(x0 * x0);
          ph1[ro] = (bf16)(x1 * x1);
        }
    __syncthreads();  // the ONLY barrier per pair

    bf16x8v kf1[2][4], kt1[4];
#pragma unroll
    for (int ot = 0; ot < 2; ++ot)
#pragma unroll
      for (int kk = 0; kk < 4; ++kk)
        kf1[ot][kk] = *(const bf16x8v*)(ktvT + tidx(h1, owt + ot, kk, l));
#pragma unroll
    for (int kk = 0; kk < 4; ++kk)
      kt1[kk] = *(const bf16x8v*)(ksb + ((h1 * 4 + kk) * 64 + l) * 8);

    {
      bf16x8v ap[2][4];
#pragma unroll
      for (int nt = 0; nt < 2; ++nt)
#pragma unroll
        for (int kk = 0; kk < 4; ++kk)
          ap[nt][kk] = *(const bf16x8v*)&ph0[sidx(nt * 16 + l15, kk * 32 + lg * 8)];
      f32x4 accN[2][2], accT[2];
#pragma unroll
      for (int nt = 0; nt < 2; ++nt) {
        accT[nt] = z4;
#pragma unroll
        for (int dt = 0; dt < 2; ++dt) accN[nt][dt] = z4;
      }
      __builtin_amdgcn_s_setprio(1);
#pragma unroll
      for (int kk = 0; kk < 4; ++kk) {
#pragma unroll
        for (int dt = 0; dt < 2; ++dt)
#pragma unroll
          for (int nt = 0; nt < 2; ++nt)
            accN[nt][dt] = mfma16(ap[nt][kk], kf0[dt][kk], accN[nt][dt]);
#pragma unroll
        for (int nt = 0; nt < 2; ++nt)
          accT[nt] = mfma16(ap[nt][kk], kt0[kk], accT[nt]);
      }
      __builtin_amdgcn_s_setprio(0);
#pragma unroll
      for (int nt = 0; nt < 2; ++nt)
#pragma unroll
        for (int r = 0; r < 4; ++r) {
          float tr = __shfl(accT[nt][r], l & 48);
          float m = 1.0f / tr;
#pragma unroll
          for (int dt = 0; dt < 2; ++dt)
            accO[nt][dt][r] = fmaf(accN[nt][dt][r], m, accO[nt][dt][r]);
        }
    }
    {
      bf16x8v ap[2][4];
#pragma unroll
      for (int nt = 0; nt < 2; ++nt)
#pragma unroll
        for (int kk = 0; kk < 4; ++kk)
          ap[nt][kk] = *(const bf16x8v*)&ph1[sidx(nt * 16 + l15, kk * 32 + lg * 8)];
      f32x4 accN[2][2], accT[2];
#pragma unroll
      for (int nt = 0; nt < 2; ++nt) {
        accT[nt] = z4;
#pragma unroll
        for (int dt = 0; dt < 2; ++dt) accN[nt][dt] = z4;
      }
      __builtin_amdgcn_s_setprio(1);
#pragma unroll
      for (int kk = 0; kk < 4; ++kk) {
#pragma unroll
        for (int dt = 0; dt < 2; ++dt)
#pragma unroll
          for (int nt = 0; nt < 2; ++nt)
            accN[nt][dt] = mfma16(ap[nt][kk], kf1[dt][kk], accN[nt][dt]);
#pragma unroll
        for (int nt = 0; nt < 2; ++nt)
          accT[nt] = mfma16(ap[nt][kk], kt1[kk], accT[nt]);
      }
      __builtin_amdgcn_s_setprio(0);
#pragma unroll
      for (int nt = 0; nt < 2; ++nt)
#pragma unroll
        for (int r = 0; r < 4; ++r) {
          float tr = __shfl(accT[nt][r], l & 48);
          float m = 1.0f / tr;
#pragma unroll
          for (int dt = 0; dt < 2; ++dt)
            accO[nt][dt][r] = fmaf(accN[nt][dt][r], m, accO[nt][dt][r]);
        }
    }
  }

  // fused vss GEMM: A-frags from srcT
  const int rb0 = blockIdx.x * 2;
#pragma unroll
  for (int kk = 0; kk < 4; ++kk) {
    bf16x8v a[2];
#pragma unroll
    for (int nt = 0; nt < 2; ++nt)
      a[nt] = *(const bf16x8v*)(srcT + (((rb0 + nt) * 4 + kk) * 64 + l) * 8);
#pragma unroll
    for (int ot = 0; ot < 2; ++ot) {
      bf16x8v bw = *(const bf16x8v*)(w2sT + tidx(0, owt + ot, kk, l));
#pragma unroll
      for (int nt = 0; nt < 2; ++nt)
        accO[nt][ot] = mfma16(a[nt], bw, accO[nt][ot]);
    }
  }
  float bb[2];
#pragma unroll
  for (int ot = 0; ot < 2; ++ot) bb[ot] = b2s[os + ot * 16 + l15];

  float ps[2][4];
#pragma unroll
  for (int nt = 0; nt < 2; ++nt)
#pragma unroll
    for (int r = 0; r < 4; ++r) ps[nt][r] = 0.f;
#pragma unroll
  for (int nt = 0; nt < 2; ++nt)
#pragma unroll
    for (int ot = 0; ot < 2; ++ot)
#pragma unroll
      for (int r = 0; r < 4; ++r) {
        float v = (accO[nt][ot][r] + bb[ot]) * 0.125f;
        accO[nt][ot][r] = v;
        ps[nt][r] += v * v;
      }
#pragma unroll
  for (int nt = 0; nt < 2; ++nt)
#pragma unroll
    for (int r = 0; r < 4; ++r) {
      float t = xred16d(ps[nt][r]);
      if (l15 == 0) s_time[w][nt * 16 + lg * 4 + r] = t;
    }
#pragma unroll
  for (int nt = 0; nt < 2; ++nt)
#pragma unroll
    for (int ot = 0; ot < 2; ++ot)
#pragma unroll
      for (int r = 0; r < 4; ++r)
        out[(nb + nt * 16 + lg * 4 + r) * 129 + 1 + os + ot * 16 + l15] = accO[nt][ot][r];
  __syncthreads();
  if (tid < QT) {
    float S = 1.0f + s_time[0][tid] + s_time[1][tid] + s_time[2][tid] + s_time[3][tid];
    out[(nb + tid) * 129] = sqrtf(S);
  }
}

// ---------------------------------------------------------------------------
extern "C" void kernel_launch(void* const* d_in, const int* in_sizes, int n_in,
                              void* d_out, int out_size, void* d_ws, size_t ws_size,
                              hipStream_t stream) {
  const float* query  = (const float*)d_in[0];
  const float* source = (const float*)d_in[1];
  const float* Wq_w   = (const float*)d_in[2];
  const float* Wq_b   = (const float*)d_in[3];
  const float* Wk_w   = (const float*)d_in[4];
  const float* Wk_b   = (const float*)d_in[5];
  const float* Wv_w   = (const float*)d_in[6];
  const float* Wv_b   = (const float*)d_in[7];
  const float* vmw    = (const float*)d_in[8];
  const float* vmb    = (const float*)d_in[9];

  char* ws = (char*)d_ws;
  bf16*  wqT       = (bf16*)(ws + 0);           // 262144
  bf16*  wkT       = (bf16*)(ws + 262144);      // 262144
  bf16*  wvT       = (bf16*)(ws + 524288);      // 262144
  bf16*  w2sT      = (bf16*)(ws + 786432);      // 32768
  float* b2s       = (float*)(ws + 819200);     // 512
  float* Wvs       = (float*)(ws + 819712);     // 65536
  float* Wvbs      = (float*)(ws + 885248);     // 512
  bf16*  ktvT      = (bf16*)(ws + 885760);      // 262144
  bf16*  ksb       = (bf16*)(ws + 1147904);     // 32768
  bf16*  srcT      = (bf16*)(ws + 1180672);     // 8388608
  float* ksum_part = (float*)(ws + 9569280);    // 262144
  bf16*  ktv_part  = (bf16*)(ws + 10093568);    // 64*262144 = 16.78 MB

  int nchunk = 64, nsub = 8;
  if (ws_size < 10093568ull + 64ull * 262144ull) { nchunk = 32; nsub = 16; }

  k_prepA<<<2560, 256, 0, stream>>>(source, Wq_w, Wk_w, Wv_w, Wv_b,
                                    srcT, wqT, wkT, wvT, Wvs, Wvbs);
  k_ktv<<<nchunk * NH, 256, 0, stream>>>(srcT, wkT, wvT, Wk_b, Wv_b,
                                         ktv_part, ksum_part, nsub, nchunk / 8);
  k_finishB<<<640, 256, 0, stream>>>(ktv_part, ksum_part, vmw, vmb, Wvs, Wvbs,
                                     ktvT, ksb, w2sT, b2s, nchunk);
  k_out<<<NTOK / QT, 256, 0, stream>>>(query, srcT, wqT, Wq_b, ktvT, ksb,
                                       w2sT, b2s, (float*)d_out);
}

// Round 17
// 106.759 us; speedup vs baseline: 1.1509x; 1.0138x over previous
//
#include <hip/hip_runtime.h>

// Problem constants
#define NTOK   32768
#define CDIM   128
#define NH     8
#define QT     32     // rows per k_out block

typedef __bf16 bf16;
typedef __bf16 bf16x4v __attribute__((ext_vector_type(4)));
typedef __bf16 bf16x8v __attribute__((ext_vector_type(8)));
typedef float  f32x4   __attribute__((ext_vector_type(4)));

__device__ __forceinline__ f32x4 mfma16(bf16x8v a, bf16x8v b, f32x4 c) {
  return __builtin_amdgcn_mfma_f32_16x16x32_bf16(a, b, c, 0, 0, 0);
}

// DPP 16-lane-group sum (pure VALU, off the DS pipe). HW-verified r8-r16.
template<int CTRL>
__device__ __forceinline__ float dpp_add(float x) {
  int y = __builtin_amdgcn_mov_dpp(__float_as_int(x), CTRL, 0xf, 0xf, true);
  return x + __int_as_float(y);
}
__device__ __forceinline__ float xred16d(float v) {
  v = dpp_add<0xB1>(v);    // quad_perm [1,0,3,2]
  v = dpp_add<0x4E>(v);    // quad_perm [2,3,0,1]
  v = dpp_add<0x141>(v);   // row_half_mirror
  v = dpp_add<0x140>(v);   // row_mirror
  return v;
}

// swizzled element index for row-major [R][128] bf16 LDS tiles
__device__ __forceinline__ int sidx(int row, int col) {
  return row * 128 + (col ^ ((row & 7) << 3));
}

// Fragment-tiled global layout: T[h][tile][kk][lane][8]
__device__ __forceinline__ int tidx(int h, int tile, int kk, int lane) {
  return (((h * 8 + tile) * 4 + kk) * 64 + lane) * 8;
}

// ---------------------------------------------------------------------------
// k_prepA: blocks [0,2048): source f32 -> bf16 A-fragment-tiled srcT.
//          blocks [2048,2560): Wq/Wk/Wv -> bf16 fragment-tiled (+Wvs/Wvbs).
// ---------------------------------------------------------------------------
__global__ void __launch_bounds__(256) k_prepA(
    const float* __restrict__ src,
    const float* __restrict__ Wq, const float* __restrict__ Wk,
    const float* __restrict__ Wv, const float* __restrict__ Wv_b,
    bf16* __restrict__ srcT,
    bf16* __restrict__ wqT, bf16* __restrict__ wkT, bf16* __restrict__ wvT,
    float* __restrict__ Wvs, float* __restrict__ Wvbs)
{
  const int bid = blockIdx.x;
  const int tid = threadIdx.x;
  if (bid < 2048) {
    const int rb = bid;
    const int row = tid >> 4, col0 = (tid & 15) * 8;
    const float* p = src + (rb * 16 + row) * CDIM + col0;
    f32x4 v0 = *(const f32x4*)p;
    f32x4 v1 = *(const f32x4*)(p + 4);
    bf16x8v o;
    o[0] = (bf16)v0[0]; o[1] = (bf16)v0[1]; o[2] = (bf16)v0[2]; o[3] = (bf16)v0[3];
    o[4] = (bf16)v1[0]; o[5] = (bf16)v1[1]; o[6] = (bf16)v1[2]; o[7] = (bf16)v1[3];
    const int kk = col0 >> 5, lg = (col0 >> 3) & 3;
    const int lane = row + 16 * lg;
    *(bf16x8v*)(srcT + ((rb * 4 + kk) * 64 + lane) * 8) = o;
  } else {
    const int b = bid - 2048;            // 0..511
    const int h = b >> 6;
    const int o = (b & 63) * 2 + (tid >> 7);
    const int i = tid & 127;
    const int s = (h * CDIM + o) * CDIM + i;
    const int ot = o >> 4, l15 = o & 15;
    const int kk = i >> 5, lg = (i >> 3) & 3, j = i & 7;
    const int dst = tidx(h, ot, kk, l15 + 16 * lg) + j;
    wqT[dst] = (bf16)Wq[s];
    wkT[dst] = (bf16)Wk[s];
    wvT[dst] = (bf16)Wv[s];
    if (h == 0) {
      float sm = 0.f;
#pragma unroll
      for (int hh = 0; hh < NH; ++hh) sm += Wv[(hh * CDIM + o) * CDIM + i];
      Wvs[o * CDIM + i] = sm;
      if (o == 0) {
        float sb = 0.f;
#pragma unroll
        for (int hh = 0; hh < NH; ++hh) sb += Wv_b[hh * CDIM + i];
        Wvbs[i] = sb;
      }
    }
  }
}

// ---------------------------------------------------------------------------
// k_ktv: r16-exact (early v-pack dbuf s_vT, DPP norms, setprio MFMA cluster,
//        XCD swizzle, fragment-order store).
// ---------------------------------------------------------------------------
__global__ void __launch_bounds__(256, 2) k_ktv(
    const bf16* __restrict__ srcT,
    const bf16* __restrict__ wkT, const bf16* __restrict__ wvT,
    const float* __restrict__ Wk_b, const float* __restrict__ Wv_b,
    bf16* __restrict__ ktv_part, float* __restrict__ ksum_part,
    int nsub, int cpx)
{
  const int x = blockIdx.x & 7;
  const int g = blockIdx.x >> 3;
  const int c = x * cpx + (g >> 3);
  const int h = g & 7;

  const int tid = threadIdx.x;
  const int w = tid >> 6, l = tid & 63;
  const int l15 = l & 15, lg = l >> 4;
  const int os = w * 32, owt = os >> 4;

  __shared__ bf16 s_phiT[128][68];
  __shared__ bf16 s_vT[2][128][68];
  __shared__ float s_red2[8][64];
  __shared__ float s_scale[64];

  const f32x4 z4 = {0.f, 0.f, 0.f, 0.f};

  bf16x8v bWk[2][4], bWv[2][4];
  float bK[2], bV[2];
#pragma unroll
  for (int ot = 0; ot < 2; ++ot) {
#pragma unroll
    for (int kk = 0; kk < 4; ++kk) {
      bWk[ot][kk] = *(const bf16x8v*)(wkT + tidx(h, owt + ot, kk, l));
      bWv[ot][kk] = *(const bf16x8v*)(wvT + tidx(h, owt + ot, kk, l));
    }
    bK[ot] = Wk_b[h * CDIM + os + ot * 16 + l15];
    bV[ot] = Wv_b[h * CDIM + os + ot * 16 + l15];
  }

  const int wd = (w >> 1) * 64, wm = (w & 1) * 64;
  f32x4 acc[4][4];
#pragma unroll
  for (int dt = 0; dt < 4; ++dt)
#pragma unroll
    for (int mt = 0; mt < 4; ++mt) acc[dt][mt] = z4;
  float ksacc[2] = {0.f, 0.f};

#pragma unroll 1
  for (int s = 0; s < nsub; ++s) {
    const int rbase = (c * nsub + s) * 4;
    const int vb = s & 1;
    f32x4 accK[4][2], accV[4][2];
#pragma unroll
    for (int nt = 0; nt < 4; ++nt)
#pragma unroll
      for (int ot = 0; ot < 2; ++ot) { accK[nt][ot] = z4; accV[nt][ot] = z4; }
#pragma unroll
    for (int kk = 0; kk < 4; ++kk) {
      bf16x8v a[4];
#pragma unroll
      for (int nt = 0; nt < 4; ++nt)
        a[nt] = *(const bf16x8v*)(srcT + (((rbase + nt) * 4 + kk) * 64 + l) * 8);
#pragma unroll
      for (int nt = 0; nt < 4; ++nt)
#pragma unroll
        for (int ot = 0; ot < 2; ++ot) {
          accK[nt][ot] = mfma16(a[nt], bWk[ot][kk], accK[nt][ot]);
          accV[nt][ot] = mfma16(a[nt], bWv[ot][kk], accV[nt][ot]);
        }
    }
    // EARLY v-pack -> s_vT[vb] (prev MFMA reads s_vT[vb^1]; no barrier needed)
#pragma unroll
    for (int nt = 0; nt < 4; ++nt)
#pragma unroll
      for (int ot = 0; ot < 2; ++ot) {
        bf16x4v vv;
#pragma unroll
        for (int r = 0; r < 4; ++r)
          vv[r] = (bf16)(accV[nt][ot][r] + bV[ot]);
        *(bf16x4v*)&s_vT[vb][os + ot * 16 + l15][nt * 16 + lg * 4] = vv;
      }
#pragma unroll
    for (int nt = 0; nt < 4; ++nt)
#pragma unroll
      for (int r = 0; r < 4; ++r) {
        float a2 = 0.f, a4 = 0.f;
#pragma unroll
        for (int ot = 0; ot < 2; ++ot) {
          float xv = fmaxf(accK[nt][ot][r] + bK[ot], 0.f) + 1e-6f;
          float x2 = xv * xv;
          accK[nt][ot][r] = x2;
          a2 += x2;
          a4 += x2 * x2;
        }
        a2 = xred16d(a2);
        a4 = xred16d(a4);
        if (l15 == 0) {
          s_red2[w * 2 + 0][nt * 16 + lg * 4 + r] = a2;
          s_red2[w * 2 + 1][nt * 16 + lg * 4 + r] = a4;
        }
      }
    __syncthreads();  // B1
    {
      float S2 = s_red2[0][l] + s_red2[2][l] + s_red2[4][l] + s_red2[6][l];
      float S4 = s_red2[1][l] + s_red2[3][l] + s_red2[5][l] + s_red2[7][l];
      s_scale[l] = sqrtf(S2) / (sqrtf(S4) + 1e-8f);
    }
#pragma unroll
    for (int nt = 0; nt < 4; ++nt) {
      f32x4 sc = *(const f32x4*)&s_scale[nt * 16 + lg * 4];
#pragma unroll
      for (int ot = 0; ot < 2; ++ot) {
        bf16x4v ph;
#pragma unroll
        for (int r = 0; r < 4; ++r) {
          float p = accK[nt][ot][r] * sc[r];
          ksacc[ot] += p;
          ph[r] = (bf16)p;
        }
        *(bf16x4v*)&s_phiT[os + ot * 16 + l15][nt * 16 + lg * 4] = ph;
      }
    }
    __syncthreads();  // B2
    __builtin_amdgcn_s_setprio(1);
#pragma unroll
    for (int kkn = 0; kkn < 2; ++kkn) {
      bf16x8v aV[4], bP[4];
#pragma unroll
      for (int dt = 0; dt < 4; ++dt)
        aV[dt] = *(const bf16x8v*)&s_vT[vb][wd + dt * 16 + l15][kkn * 32 + lg * 8];
#pragma unroll
      for (int mt = 0; mt < 4; ++mt)
        bP[mt] = *(const bf16x8v*)&s_phiT[wm + mt * 16 + l15][kkn * 32 + lg * 8];
#pragma unroll
      for (int dt = 0; dt < 4; ++dt)
#pragma unroll
        for (int mt = 0; mt < 4; ++mt)
          acc[dt][mt] = mfma16(aV[dt], bP[mt], acc[dt][mt]);
    }
    __builtin_amdgcn_s_setprio(0);
  }

#pragma unroll
  for (int ot = 0; ot < 2; ++ot) {
    ksacc[ot] += __shfl_xor(ksacc[ot], 16);
    ksacc[ot] += __shfl_xor(ksacc[ot], 32);
  }
  if (l < 16) {
#pragma unroll
    for (int ot = 0; ot < 2; ++ot)
      ksum_part[(c * NH + h) * CDIM + os + ot * 16 + l] = ksacc[ot];
  }
  bf16* kp = ktv_part + ((c * NH + h) * 4 + w) * 4096;
#pragma unroll
  for (int dt = 0; dt < 4; ++dt)
#pragma unroll
    for (int mt = 0; mt < 4; ++mt) {
      bf16x4v q;
#pragma unroll
      for (int r = 0; r < 4; ++r) q[r] = (bf16)acc[dt][mt][r];
      *(bf16x4v*)(kp + ((dt * 4 + mt) * 64 + l) * 4) = q;
    }
}

// ---------------------------------------------------------------------------
// k_finishB: [0,512): ktvT reduce with COALESCED reads — thread owns linear
//            fragment-order index t, reads ktv_part[c*131072+t] (contiguous
//            per wave), decodes t->(h,d,m) for the small scattered write.
//            [512,576): ksb reduce; [576,640): prep2.
// ---------------------------------------------------------------------------
__global__ void __launch_bounds__(256) k_finishB(
    const bf16* __restrict__ ktv_part, const float* __restrict__ ksum_part,
    const float* __restrict__ vmw, const float* __restrict__ vmb,
    const float* __restrict__ Wvs, const float* __restrict__ Wvbs,
    bf16* __restrict__ ktvT, bf16* __restrict__ ksb,
    bf16* __restrict__ w2sT, float* __restrict__ b2s, int nchunk)
{
  const int b = blockIdx.x;
  if (b < 512) {
    const int t = b * 256 + threadIdx.x;          // linear fragment-order idx
    float a = 0.f;
    for (int c = 0; c < nchunk; ++c)
      a += (float)ktv_part[c * (NH * 4 * 4096) + t];
    // decode t -> (h, wq, frag, lane, r) -> (d, m)   [inverse of k_ktv store]
    const int h    = t >> 14;
    const int rem  = t & 16383;
    const int wq   = rem >> 12;
    const int frag = (rem >> 8) & 15;       // dt*4 + mt
    const int lane = (rem >> 2) & 63;
    const int r    = rem & 3;
    const int d = ((wq >> 1) << 6) + (frag >> 2) * 16 + (lane >> 4) * 4 + r;
    const int m = ((wq & 1) << 6) + (frag & 3) * 16 + (lane & 15);
    const int dtile = d >> 4, dl15 = d & 15;
    const int kk = m >> 5, mlg = (m >> 3) & 3, j = m & 7;
    ktvT[tidx(h, dtile, kk, dl15 + 16 * mlg) + j] = (bf16)a;
  } else if (b < 576) {
    const int t = (b - 512) * 256 + threadIdx.x;  // < 16384
    const int h = t >> 11;
    const int rem = t & 2047;
    const int kk = rem >> 9, lane = (rem >> 3) & 63, j = rem & 7;
    const int l15 = lane & 15, lg = lane >> 4;
    float a = 0.f;
    if (l15 == 0) {
      const int m = 32 * kk + 8 * lg + j;
      for (int c = 0; c < nchunk; ++c) a += ksum_part[(c * NH + h) * CDIM + m];
    }
    ksb[t] = (bf16)a;
  } else {
    const int sub = threadIdx.x >> 7, i = threadIdx.x & 127;
    const int o = (b - 576) * 2 + sub;
    __shared__ float s_vm[2][128];
    __shared__ float s_rd[2][128];
    s_vm[sub][i] = vmw[o * CDIM + i];
    __syncthreads();
    float acc = 0.f;
    for (int d = 0; d < CDIM; ++d) acc = fmaf(s_vm[sub][d], Wvs[d * CDIM + i], acc);
    const int ot = o >> 4, l15 = o & 15;
    const int kk = i >> 5, lg = (i >> 3) & 3, j = i & 7;
    w2sT[tidx(0, ot, kk, l15 + 16 * lg) + j] = (bf16)acc;
    s_rd[sub][i] = s_vm[sub][i] * Wvbs[i];
    __syncthreads();
    for (int st = 64; st > 0; st >>= 1) {
      if (i < st) s_rd[sub][i] += s_rd[sub][i + st];
      __syncthreads();
    }
    if (i == 0) b2s[o] = s_rd[sub][0] + 8.f * vmb[o];
  }
}

// ---------------------------------------------------------------------------
// k_out: r16 structure (two heads/iteration, pair-double-buffered phi) +
//        setprio extended to the qs-GEMM cluster (pure-register MFMA).
// ---------------------------------------------------------------------------
__global__ void __launch_bounds__(256, 2) k_out(
    const float* __restrict__ query, const bf16* __restrict__ srcT,
    const bf16* __restrict__ wqT, const float* __restrict__ Wq_b,
    const bf16* __restrict__ ktvT, const bf16* __restrict__ ksb,
    const bf16* __restrict__ w2sT, const float* __restrict__ b2s,
    float* __restrict__ out)
{
  const int nb = blockIdx.x * QT;
  const int tid = threadIdx.x;
  const int w = tid >> 6, l = tid & 63;
  const int l15 = l & 15, lg = l >> 4;
  const int os = w * 32, owt = os >> 4;

  __shared__ bf16 s_q[QT * 128];
  __shared__ bf16 s_phi[2][2][QT * 128];
  __shared__ float s_time[4][QT] __attribute__((aligned(16)));

  const f32x4 z4 = {0.f, 0.f, 0.f, 0.f};

#pragma unroll
  for (int j = 0; j < 4; ++j) {
    const int flat = tid + j * 256;
    const int n = flat >> 5, c4 = (flat & 31) * 4;
    f32x4 vq = *(const f32x4*)(query + (nb + n) * CDIM + c4);
    bf16x4v bq;
    bq[0] = (bf16)vq[0]; bq[1] = (bf16)vq[1]; bq[2] = (bf16)vq[2]; bq[3] = (bf16)vq[3];
    *(bf16x4v*)&s_q[sidx(n, c4)] = bq;
  }

  f32x4 accO[2][2];
#pragma unroll
  for (int nt = 0; nt < 2; ++nt)
#pragma unroll
    for (int ot = 0; ot < 2; ++ot) accO[nt][ot] = z4;

  __syncthreads();

  bf16x8v aq[2][4];
#pragma unroll
  for (int nt = 0; nt < 2; ++nt)
#pragma unroll
    for (int kk = 0; kk < 4; ++kk)
      aq[nt][kk] = *(const bf16x8v*)&s_q[sidx(nt * 16 + l15, kk * 32 + lg * 8)];

#pragma unroll 1
  for (int hp = 0; hp < 4; ++hp) {
    const int h0 = hp * 2, h1 = h0 + 1;
    const int pb = hp & 1;
    bf16x8v wf0[2][4], wf1[2][4], kf0[2][4], kt0[4];
#pragma unroll
    for (int ot = 0; ot < 2; ++ot)
#pragma unroll
      for (int kk = 0; kk < 4; ++kk) {
        wf0[ot][kk] = *(const bf16x8v*)(wqT + tidx(h0, owt + ot, kk, l));
        wf1[ot][kk] = *(const bf16x8v*)(wqT + tidx(h1, owt + ot, kk, l));
        kf0[ot][kk] = *(const bf16x8v*)(ktvT + tidx(h0, owt + ot, kk, l));
      }
#pragma unroll
    for (int kk = 0; kk < 4; ++kk)
      kt0[kk] = *(const bf16x8v*)(ksb + ((h0 * 4 + kk) * 64 + l) * 8);
    float bQ0[2], bQ1[2];
#pragma unroll
    for (int ot = 0; ot < 2; ++ot) {
      bQ0[ot] = Wq_b[h0 * CDIM + os + ot * 16 + l15];
      bQ1[ot] = Wq_b[h1 * CDIM + os + ot * 16 + l15];
    }

    f32x4 accQ0[2][2], accQ1[2][2];
#pragma unroll
    for (int nt = 0; nt < 2; ++nt)
#pragma unroll
      for (int ot = 0; ot < 2; ++ot) { accQ0[nt][ot] = z4; accQ1[nt][ot] = z4; }
    __builtin_amdgcn_s_setprio(1);
#pragma unroll
    for (int kk = 0; kk < 4; ++kk)
#pragma unroll
      for (int ot = 0; ot < 2; ++ot)
#pragma unroll
        for (int nt = 0; nt < 2; ++nt) {
          accQ0[nt][ot] = mfma16(aq[nt][kk], wf0[ot][kk], accQ0[nt][ot]);
          accQ1[nt][ot] = mfma16(aq[nt][kk], wf1[ot][kk], accQ1[nt][ot]);
        }
    __builtin_amdgcn_s_setprio(0);

    bf16* ph0 = s_phi[pb][0];
    bf16* ph1 = s_phi[pb][1];
#pragma unroll
    for (int nt = 0; nt < 2; ++nt)
#pragma unroll
      for (int ot = 0; ot < 2; ++ot)
#pragma unroll
        for (int r = 0; r < 4; ++r) {
          const int ro = sidx(nt * 16 + lg * 4 + r, os + ot * 16 + l15);
          float x0 = fmaxf(accQ0[nt][ot][r] + bQ0[ot], 0.f) + 1e-6f;
          float x1 = fmaxf(accQ1[nt][ot][r] + bQ1[ot], 0.f) + 1e-6f;
          ph0[ro] = (bf16)(x0 * x0);
          ph1[ro] = (bf16)(x1 * x1);
        }
    __syncthreads();  // the ONLY barrier per pair

    bf16x8v kf1[2][4], kt1[4];
#pragma unroll
    for (int ot = 0; ot < 2; ++ot)
#pragma unroll
      for (int kk = 0; kk < 4; ++kk)
        kf1[ot][kk] = *(const bf16x8v*)(ktvT + tidx(h1, owt + ot, kk, l));
#pragma unroll
    for (int kk = 0; kk < 4; ++kk)
      kt1[kk] = *(const bf16x8v*)(ksb + ((h1 * 4 + kk) * 64 + l) * 8);

    {
      bf16x8v ap[2][4];
#pragma unroll
      for (int nt = 0; nt < 2; ++nt)
#pragma unroll
        for (int kk = 0; kk < 4; ++kk)
          ap[nt][kk] = *(const bf16x8v*)&ph0[sidx(nt * 16 + l15, kk * 32 + lg * 8)];
      f32x4 accN[2][2], accT[2];
#pragma unroll
      for (int nt = 0; nt < 2; ++nt) {
        accT[nt] = z4;
#pragma unroll
        for (int dt = 0; dt < 2; ++dt) accN[nt][dt] = z4;
      }
      __builtin_amdgcn_s_setprio(1);
#pragma unroll
      for (int kk = 0; kk < 4; ++kk) {
#pragma unroll
        for (int dt = 0; dt < 2; ++dt)
#pragma unroll
          for (int nt = 0; nt < 2; ++nt)
            accN[nt][dt] = mfma16(ap[nt][kk], kf0[dt][kk], accN[nt][dt]);
#pragma unroll
        for (int nt = 0; nt < 2; ++nt)
          accT[nt] = mfma16(ap[nt][kk], kt0[kk], accT[nt]);
      }
      __builtin_amdgcn_s_setprio(0);
#pragma unroll
      for (int nt = 0; nt < 2; ++nt)
#pragma unroll
        for (int r = 0; r < 4; ++r) {
          float tr = __shfl(accT[nt][r], l & 48);
          float m = 1.0f / tr;
#pragma unroll
          for (int dt = 0; dt < 2; ++dt)
            accO[nt][dt][r] = fmaf(accN[nt][dt][r], m, accO[nt][dt][r]);
        }
    }
    {
      bf16x8v ap[2][4];
#pragma unroll
      for (int nt = 0; nt < 2; ++nt)
#pragma unroll
        for (int kk = 0; kk < 4; ++kk)
          ap[nt][kk] = *(const bf16x8v*)&ph1[sidx(nt * 16 + l15, kk * 32 + lg * 8)];
      f32x4 accN[2][2], accT[2];
#pragma unroll
      for (int nt = 0; nt < 2; ++nt) {
        accT[nt] = z4;
#pragma unroll
        for (int dt = 0; dt < 2; ++dt) accN[nt][dt] = z4;
      }
      __builtin_amdgcn_s_setprio(1);
#pragma unroll
      for (int kk = 0; kk < 4; ++kk) {
#pragma unroll
        for (int dt = 0; dt < 2; ++dt)
#pragma unroll
          for (int nt = 0; nt < 2; ++nt)
            accN[nt][dt] = mfma16(ap[nt][kk], kf1[dt][kk], accN[nt][dt]);
#pragma unroll
        for (int nt = 0; nt < 2; ++nt)
          accT[nt] = mfma16(ap[nt][kk], kt1[kk], accT[nt]);
      }
      __builtin_amdgcn_s_setprio(0);
#pragma unroll
      for (int nt = 0; nt < 2; ++nt)
#pragma unroll
        for (int r = 0; r < 4; ++r) {
          float tr = __shfl(accT[nt][r], l & 48);
          float m = 1.0f / tr;
#pragma unroll
          for (int dt = 0; dt < 2; ++dt)
            accO[nt][dt][r] = fmaf(accN[nt][dt][r], m, accO[nt][dt][r]);
        }
    }
  }

  // fused vss GEMM: A-frags from srcT
  const int rb0 = blockIdx.x * 2;
#pragma unroll
  for (int kk = 0; kk < 4; ++kk) {
    bf16x8v a[2];
#pragma unroll
    for (int nt = 0; nt < 2; ++nt)
      a[nt] = *(const bf16x8v*)(srcT + (((rb0 + nt) * 4 + kk) * 64 + l) * 8);
#pragma unroll
    for (int ot = 0; ot < 2; ++ot) {
      bf16x8v bw = *(const bf16x8v*)(w2sT + tidx(0, owt + ot, kk, l));
#pragma unroll
      for (int nt = 0; nt < 2; ++nt)
        accO[nt][ot] = mfma16(a[nt], bw, accO[nt][ot]);
    }
  }
  float bb[2];
#pragma unroll
  for (int ot = 0; ot < 2; ++ot) bb[ot] = b2s[os + ot * 16 + l15];

  float ps[2][4];
#pragma unroll
  for (int nt = 0; nt < 2; ++nt)
#pragma unroll
    for (int r = 0; r < 4; ++r) ps[nt][r] = 0.f;
#pragma unroll
  for (int nt = 0; nt < 2; ++nt)
#pragma unroll
    for (int ot = 0; ot < 2; ++ot)
#pragma unroll
      for (int r = 0; r < 4; ++r) {
        float v = (accO[nt][ot][r] + bb[ot]) * 0.125f;
        accO[nt][ot][r] = v;
        ps[nt][r] += v * v;
      }
#pragma unroll
  for (int nt = 0; nt < 2; ++nt)
#pragma unroll
    for (int r = 0; r < 4; ++r) {
      float t = xred16d(ps[nt][r]);
      if (l15 == 0) s_time[w][nt * 16 + lg * 4 + r] = t;
    }
#pragma unroll
  for (int nt = 0; nt < 2; ++nt)
#pragma unroll
    for (int ot = 0; ot < 2; ++ot)
#pragma unroll
      for (int r = 0; r < 4; ++r)
        out[(nb + nt * 16 + lg * 4 + r) * 129 + 1 + os + ot * 16 + l15] = accO[nt][ot][r];
  __syncthreads();
  if (tid < QT) {
    float S = 1.0f + s_time[0][tid] + s_time[1][tid] + s_time[2][tid] + s_time[3][tid];
    out[(nb + tid) * 129] = sqrtf(S);
  }
}

// ---------------------------------------------------------------------------
extern "C" void kernel_launch(void* const* d_in, const int* in_sizes, int n_in,
                              void* d_out, int out_size, void* d_ws, size_t ws_size,
                              hipStream_t stream) {
  const float* query  = (const float*)d_in[0];
  const float* source = (const float*)d_in[1];
  const float* Wq_w   = (const float*)d_in[2];
  const float* Wq_b   = (const float*)d_in[3];
  const float* Wk_w   = (const float*)d_in[4];
  const float* Wk_b   = (const float*)d_in[5];
  const float* Wv_w   = (const float*)d_in[6];
  const float* Wv_b   = (const float*)d_in[7];
  const float* vmw    = (const float*)d_in[8];
  const float* vmb    = (const float*)d_in[9];

  char* ws = (char*)d_ws;
  bf16*  wqT       = (bf16*)(ws + 0);           // 262144
  bf16*  wkT       = (bf16*)(ws + 262144);      // 262144
  bf16*  wvT       = (bf16*)(ws + 524288);      // 262144
  bf16*  w2sT      = (bf16*)(ws + 786432);      // 32768
  float* b2s       = (float*)(ws + 819200);     // 512
  float* Wvs       = (float*)(ws + 819712);     // 65536
  float* Wvbs      = (float*)(ws + 885248);     // 512
  bf16*  ktvT      = (bf16*)(ws + 885760);      // 262144
  bf16*  ksb       = (bf16*)(ws + 1147904);     // 32768
  bf16*  srcT      = (bf16*)(ws + 1180672);     // 8388608
  float* ksum_part = (float*)(ws + 9569280);    // 262144
  bf16*  ktv_part  = (bf16*)(ws + 10093568);    // 64*262144 = 16.78 MB

  int nchunk = 64, nsub = 8;
  if (ws_size < 10093568ull + 64ull * 262144ull) { nchunk = 32; nsub = 16; }

  k_prepA<<<2560, 256, 0, stream>>>(source, Wq_w, Wk_w, Wv_w, Wv_b,
                                    srcT, wqT, wkT, wvT, Wvs, Wvbs);
  k_ktv<<<nchunk * NH, 256, 0, stream>>>(srcT, wkT, wvT, Wk_b, Wv_b,
                                         ktv_part, ksum_part, nsub, nchunk / 8);
  k_finishB<<<640, 256, 0, stream>>>(ktv_part, ksum_part, vmw, vmb, Wvs, Wvbs,
                                     ktvT, ksb, w2sT, b2s, nchunk);
  k_out<<<NTOK / QT, 256, 0, stream>>>(query, srcT, wqT, Wq_b, ktvT, ksb,
                                       w2sT, b2s, (float*)d_out);
}

// Round 19
// 106.707 us; speedup vs baseline: 1.1515x; 1.0005x over previous
//
#include <hip/hip_runtime.h>

// Problem constants
#define NTOK   32768
#define CDIM   128
#define NH     8
#define QT     32     // rows per k_out block

typedef __bf16 bf16;
typedef __bf16 bf16x4v __attribute__((ext_vector_type(4)));
typedef __bf16 bf16x8v __attribute__((ext_vector_type(8)));
typedef float  f32x4   __attribute__((ext_vector_type(4)));

__device__ __forceinline__ f32x4 mfma16(bf16x8v a, bf16x8v b, f32x4 c) {
  return __builtin_amdgcn_mfma_f32_16x16x32_bf16(a, b, c, 0, 0, 0);
}

// DPP 16-lane-group sum (pure VALU, off the DS pipe). HW-verified r8-r17.
template<int CTRL>
__device__ __forceinline__ float dpp_add(float x) {
  int y = __builtin_amdgcn_mov_dpp(__float_as_int(x), CTRL, 0xf, 0xf, true);
  return x + __int_as_float(y);
}
__device__ __forceinline__ float xred16d(float v) {
  v = dpp_add<0xB1>(v);    // quad_perm [1,0,3,2]
  v = dpp_add<0x4E>(v);    // quad_perm [2,3,0,1]
  v = dpp_add<0x141>(v);   // row_half_mirror
  v = dpp_add<0x140>(v);   // row_mirror
  return v;
}

// swizzled element index for row-major [R][128] bf16 LDS tiles
__device__ __forceinline__ int sidx(int row, int col) {
  return row * 128 + (col ^ ((row & 7) << 3));
}

// Fragment-tiled global layout: T[h][tile][kk][lane][8]
__device__ __forceinline__ int tidx(int h, int tile, int kk, int lane) {
  return (((h * 8 + tile) * 4 + kk) * 64 + lane) * 8;
}

// ---------------------------------------------------------------------------
// k_prepA: blocks [0,2048): source f32 -> bf16 A-fragment-tiled srcT.
//          blocks [2048,2560): Wq/Wk/Wv -> bf16 fragment-tiled (+Wvs/Wvbs).
// ---------------------------------------------------------------------------
__global__ void __launch_bounds__(256) k_prepA(
    const float* __restrict__ src,
    const float* __restrict__ Wq, const float* __restrict__ Wk,
    const float* __restrict__ Wv, const float* __restrict__ Wv_b,
    bf16* __restrict__ srcT,
    bf16* __restrict__ wqT, bf16* __restrict__ wkT, bf16* __restrict__ wvT,
    float* __restrict__ Wvs, float* __restrict__ Wvbs)
{
  const int bid = blockIdx.x;
  const int tid = threadIdx.x;
  if (bid < 2048) {
    const int rb = bid;
    const int row = tid >> 4, col0 = (tid & 15) * 8;
    const float* p = src + (rb * 16 + row) * CDIM + col0;
    f32x4 v0 = *(const f32x4*)p;
    f32x4 v1 = *(const f32x4*)(p + 4);
    bf16x8v o;
    o[0] = (bf16)v0[0]; o[1] = (bf16)v0[1]; o[2] = (bf16)v0[2]; o[3] = (bf16)v0[3];
    o[4] = (bf16)v1[0]; o[5] = (bf16)v1[1]; o[6] = (bf16)v1[2]; o[7] = (bf16)v1[3];
    const int kk = col0 >> 5, lg = (col0 >> 3) & 3;
    const int lane = row + 16 * lg;
    *(bf16x8v*)(srcT + ((rb * 4 + kk) * 64 + lane) * 8) = o;
  } else {
    const int b = bid - 2048;            // 0..511
    const int h = b >> 6;
    const int o = (b & 63) * 2 + (tid >> 7);
    const int i = tid & 127;
    const int s = (h * CDIM + o) * CDIM + i;
    const int ot = o >> 4, l15 = o & 15;
    const int kk = i >> 5, lg = (i >> 3) & 3, j = i & 7;
    const int dst = tidx(h, ot, kk, l15 + 16 * lg) + j;
    wqT[dst] = (bf16)Wq[s];
    wkT[dst] = (bf16)Wk[s];
    wvT[dst] = (bf16)Wv[s];
    if (h == 0) {
      float sm = 0.f;
#pragma unroll
      for (int hh = 0; hh < NH; ++hh) sm += Wv[(hh * CDIM + o) * CDIM + i];
      Wvs[o * CDIM + i] = sm;
      if (o == 0) {
        float sb = 0.f;
#pragma unroll
        for (int hh = 0; hh < NH; ++hh) sb += Wv_b[hh * CDIM + i];
        Wvbs[i] = sb;
      }
    }
  }
}

// ---------------------------------------------------------------------------
// k_ktv: r16-exact (early v-pack dbuf s_vT, DPP norms, setprio MFMA cluster,
//        XCD swizzle, fragment-order store).
// ---------------------------------------------------------------------------
__global__ void __launch_bounds__(256, 2) k_ktv(
    const bf16* __restrict__ srcT,
    const bf16* __restrict__ wkT, const bf16* __restrict__ wvT,
    const float* __restrict__ Wk_b, const float* __restrict__ Wv_b,
    bf16* __restrict__ ktv_part, float* __restrict__ ksum_part,
    int nsub, int cpx)
{
  const int x = blockIdx.x & 7;
  const int g = blockIdx.x >> 3;
  const int c = x * cpx + (g >> 3);
  const int h = g & 7;

  const int tid = threadIdx.x;
  const int w = tid >> 6, l = tid & 63;
  const int l15 = l & 15, lg = l >> 4;
  const int os = w * 32, owt = os >> 4;

  __shared__ bf16 s_phiT[128][68];
  __shared__ bf16 s_vT[2][128][68];
  __shared__ float s_red2[8][64];
  __shared__ float s_scale[64];

  const f32x4 z4 = {0.f, 0.f, 0.f, 0.f};

  bf16x8v bWk[2][4], bWv[2][4];
  float bK[2], bV[2];
#pragma unroll
  for (int ot = 0; ot < 2; ++ot) {
#pragma unroll
    for (int kk = 0; kk < 4; ++kk) {
      bWk[ot][kk] = *(const bf16x8v*)(wkT + tidx(h, owt + ot, kk, l));
      bWv[ot][kk] = *(const bf16x8v*)(wvT + tidx(h, owt + ot, kk, l));
    }
    bK[ot] = Wk_b[h * CDIM + os + ot * 16 + l15];
    bV[ot] = Wv_b[h * CDIM + os + ot * 16 + l15];
  }

  const int wd = (w >> 1) * 64, wm = (w & 1) * 64;
  f32x4 acc[4][4];
#pragma unroll
  for (int dt = 0; dt < 4; ++dt)
#pragma unroll
    for (int mt = 0; mt < 4; ++mt) acc[dt][mt] = z4;
  float ksacc[2] = {0.f, 0.f};

#pragma unroll 1
  for (int s = 0; s < nsub; ++s) {
    const int rbase = (c * nsub + s) * 4;
    const int vb = s & 1;
    f32x4 accK[4][2], accV[4][2];
#pragma unroll
    for (int nt = 0; nt < 4; ++nt)
#pragma unroll
      for (int ot = 0; ot < 2; ++ot) { accK[nt][ot] = z4; accV[nt][ot] = z4; }
#pragma unroll
    for (int kk = 0; kk < 4; ++kk) {
      bf16x8v a[4];
#pragma unroll
      for (int nt = 0; nt < 4; ++nt)
        a[nt] = *(const bf16x8v*)(srcT + (((rbase + nt) * 4 + kk) * 64 + l) * 8);
#pragma unroll
      for (int nt = 0; nt < 4; ++nt)
#pragma unroll
        for (int ot = 0; ot < 2; ++ot) {
          accK[nt][ot] = mfma16(a[nt], bWk[ot][kk], accK[nt][ot]);
          accV[nt][ot] = mfma16(a[nt], bWv[ot][kk], accV[nt][ot]);
        }
    }
    // EARLY v-pack -> s_vT[vb] (prev MFMA reads s_vT[vb^1]; no barrier needed)
#pragma unroll
    for (int nt = 0; nt < 4; ++nt)
#pragma unroll
      for (int ot = 0; ot < 2; ++ot) {
        bf16x4v vv;
#pragma unroll
        for (int r = 0; r < 4; ++r)
          vv[r] = (bf16)(accV[nt][ot][r] + bV[ot]);
        *(bf16x4v*)&s_vT[vb][os + ot * 16 + l15][nt * 16 + lg * 4] = vv;
      }
#pragma unroll
    for (int nt = 0; nt < 4; ++nt)
#pragma unroll
      for (int r = 0; r < 4; ++r) {
        float a2 = 0.f, a4 = 0.f;
#pragma unroll
        for (int ot = 0; ot < 2; ++ot) {
          float xv = fmaxf(accK[nt][ot][r] + bK[ot], 0.f) + 1e-6f;
          float x2 = xv * xv;
          accK[nt][ot][r] = x2;
          a2 += x2;
          a4 += x2 * x2;
        }
        a2 = xred16d(a2);
        a4 = xred16d(a4);
        if (l15 == 0) {
          s_red2[w * 2 + 0][nt * 16 + lg * 4 + r] = a2;
          s_red2[w * 2 + 1][nt * 16 + lg * 4 + r] = a4;
        }
      }
    __syncthreads();  // B1
    {
      float S2 = s_red2[0][l] + s_red2[2][l] + s_red2[4][l] + s_red2[6][l];
      float S4 = s_red2[1][l] + s_red2[3][l] + s_red2[5][l] + s_red2[7][l];
      s_scale[l] = sqrtf(S2) / (sqrtf(S4) + 1e-8f);
    }
#pragma unroll
    for (int nt = 0; nt < 4; ++nt) {
      f32x4 sc = *(const f32x4*)&s_scale[nt * 16 + lg * 4];
#pragma unroll
      for (int ot = 0; ot < 2; ++ot) {
        bf16x4v ph;
#pragma unroll
        for (int r = 0; r < 4; ++r) {
          float p = accK[nt][ot][r] * sc[r];
          ksacc[ot] += p;
          ph[r] = (bf16)p;
        }
        *(bf16x4v*)&s_phiT[os + ot * 16 + l15][nt * 16 + lg * 4] = ph;
      }
    }
    __syncthreads();  // B2
    __builtin_amdgcn_s_setprio(1);
#pragma unroll
    for (int kkn = 0; kkn < 2; ++kkn) {
      bf16x8v aV[4], bP[4];
#pragma unroll
      for (int dt = 0; dt < 4; ++dt)
        aV[dt] = *(const bf16x8v*)&s_vT[vb][wd + dt * 16 + l15][kkn * 32 + lg * 8];
#pragma unroll
      for (int mt = 0; mt < 4; ++mt)
        bP[mt] = *(const bf16x8v*)&s_phiT[wm + mt * 16 + l15][kkn * 32 + lg * 8];
#pragma unroll
      for (int dt = 0; dt < 4; ++dt)
#pragma unroll
        for (int mt = 0; mt < 4; ++mt)
          acc[dt][mt] = mfma16(aV[dt], bP[mt], acc[dt][mt]);
    }
    __builtin_amdgcn_s_setprio(0);
  }

#pragma unroll
  for (int ot = 0; ot < 2; ++ot) {
    ksacc[ot] += __shfl_xor(ksacc[ot], 16);
    ksacc[ot] += __shfl_xor(ksacc[ot], 32);
  }
  if (l < 16) {
#pragma unroll
    for (int ot = 0; ot < 2; ++ot)
      ksum_part[(c * NH + h) * CDIM + os + ot * 16 + l] = ksacc[ot];
  }
  bf16* kp = ktv_part + ((c * NH + h) * 4 + w) * 4096;
#pragma unroll
  for (int dt = 0; dt < 4; ++dt)
#pragma unroll
    for (int mt = 0; mt < 4; ++mt) {
      bf16x4v q;
#pragma unroll
      for (int r = 0; r < 4; ++r) q[r] = (bf16)acc[dt][mt][r];
      *(bf16x4v*)(kp + ((dt * 4 + mt) * 64 + l) * 4) = q;
    }
}

// ---------------------------------------------------------------------------
// k_finishB: r17-exact (coalesced fragment-order reduce + decode).
// ---------------------------------------------------------------------------
__global__ void __launch_bounds__(256) k_finishB(
    const bf16* __restrict__ ktv_part, const float* __restrict__ ksum_part,
    const float* __restrict__ vmw, const float* __restrict__ vmb,
    const float* __restrict__ Wvs, const float* __restrict__ Wvbs,
    bf16* __restrict__ ktvT, bf16* __restrict__ ksb,
    bf16* __restrict__ w2sT, float* __restrict__ b2s, int nchunk)
{
  const int b = blockIdx.x;
  if (b < 512) {
    const int t = b * 256 + threadIdx.x;          // linear fragment-order idx
    float a = 0.f;
    for (int c = 0; c < nchunk; ++c)
      a += (float)ktv_part[c * (NH * 4 * 4096) + t];
    const int h    = t >> 14;
    const int rem  = t & 16383;
    const int wq   = rem >> 12;
    const int frag = (rem >> 8) & 15;       // dt*4 + mt
    const int lane = (rem >> 2) & 63;
    const int r    = rem & 3;
    const int d = ((wq >> 1) << 6) + (frag >> 2) * 16 + (lane >> 4) * 4 + r;
    const int m = ((wq & 1) << 6) + (frag & 3) * 16 + (lane & 15);
    const int dtile = d >> 4, dl15 = d & 15;
    const int kk = m >> 5, mlg = (m >> 3) & 3, j = m & 7;
    ktvT[tidx(h, dtile, kk, dl15 + 16 * mlg) + j] = (bf16)a;
  } else if (b < 576) {
    const int t = (b - 512) * 256 + threadIdx.x;  // < 16384
    const int h = t >> 11;
    const int rem = t & 2047;
    const int kk = rem >> 9, lane = (rem >> 3) & 63, j = rem & 7;
    const int l15 = lane & 15, lg = lane >> 4;
    float a = 0.f;
    if (l15 == 0) {
      const int m = 32 * kk + 8 * lg + j;
      for (int c = 0; c < nchunk; ++c) a += ksum_part[(c * NH + h) * CDIM + m];
    }
    ksb[t] = (bf16)a;
  } else {
    const int sub = threadIdx.x >> 7, i = threadIdx.x & 127;
    const int o = (b - 576) * 2 + sub;
    __shared__ float s_vm[2][128];
    __shared__ float s_rd[2][128];
    s_vm[sub][i] = vmw[o * CDIM + i];
    __syncthreads();
    float acc = 0.f;
    for (int d = 0; d < CDIM; ++d) acc = fmaf(s_vm[sub][d], Wvs[d * CDIM + i], acc);
    const int ot = o >> 4, l15 = o & 15;
    const int kk = i >> 5, lg = (i >> 3) & 3, j = i & 7;
    w2sT[tidx(0, ot, kk, l15 + 16 * lg) + j] = (bf16)acc;
    s_rd[sub][i] = s_vm[sub][i] * Wvbs[i];
    __syncthreads();
    for (int st = 64; st > 0; st >>= 1) {
      if (i < st) s_rd[sub][i] += s_rd[sub][i + st];
      __syncthreads();
    }
    if (i == 0) b2s[o] = s_rd[sub][0] + 8.f * vmb[o];
  }
}

// ---------------------------------------------------------------------------
// k_out: r17-exact (two heads/iteration, pair-double-buffered phi, setprio;
//        __launch_bounds__(256,2) — (256,3) broke replay determinism in r18).
// ---------------------------------------------------------------------------
__global__ void __launch_bounds__(256, 2) k_out(
    const float* __restrict__ query, const bf16* __restrict__ srcT,
    const bf16* __restrict__ wqT, const float* __restrict__ Wq_b,
    const bf16* __restrict__ ktvT, const bf16* __restrict__ ksb,
    const bf16* __restrict__ w2sT, const float* __restrict__ b2s,
    float* __restrict__ out)
{
  const int nb = blockIdx.x * QT;
  const int tid = threadIdx.x;
  const int w = tid >> 6, l = tid & 63;
  const int l15 = l & 15, lg = l >> 4;
  const int os = w * 32, owt = os >> 4;

  __shared__ bf16 s_q[QT * 128];
  __shared__ bf16 s_phi[2][2][QT * 128];
  __shared__ float s_time[4][QT] __attribute__((aligned(16)));

  const f32x4 z4 = {0.f, 0.f, 0.f, 0.f};

#pragma unroll
  for (int j = 0; j < 4; ++j) {
    const int flat = tid + j * 256;
    const int n = flat >> 5, c4 = (flat & 31) * 4;
    f32x4 vq = *(const f32x4*)(query + (nb + n) * CDIM + c4);
    bf16x4v bq;
    bq[0] = (bf16)vq[0]; bq[1] = (bf16)vq[1]; bq[2] = (bf16)vq[2]; bq[3] = (bf16)vq[3];
    *(bf16x4v*)&s_q[sidx(n, c4)] = bq;
  }

  f32x4 accO[2][2];
#pragma unroll
  for (int nt = 0; nt < 2; ++nt)
#pragma unroll
    for (int ot = 0; ot < 2; ++ot) accO[nt][ot] = z4;

  __syncthreads();

  bf16x8v aq[2][4];
#pragma unroll
  for (int nt = 0; nt < 2; ++nt)
#pragma unroll
    for (int kk = 0; kk < 4; ++kk)
      aq[nt][kk] = *(const bf16x8v*)&s_q[sidx(nt * 16 + l15, kk * 32 + lg * 8)];

#pragma unroll 1
  for (int hp = 0; hp < 4; ++hp) {
    const int h0 = hp * 2, h1 = h0 + 1;
    const int pb = hp & 1;
    bf16x8v wf0[2][4], wf1[2][4], kf0[2][4], kt0[4];
#pragma unroll
    for (int ot = 0; ot < 2; ++ot)
#pragma unroll
      for (int kk = 0; kk < 4; ++kk) {
        wf0[ot][kk] = *(const bf16x8v*)(wqT + tidx(h0, owt + ot, kk, l));
        wf1[ot][kk] = *(const bf16x8v*)(wqT + tidx(h1, owt + ot, kk, l));
        kf0[ot][kk] = *(const bf16x8v*)(ktvT + tidx(h0, owt + ot, kk, l));
      }
#pragma unroll
    for (int kk = 0; kk < 4; ++kk)
      kt0[kk] = *(const bf16x8v*)(ksb + ((h0 * 4 + kk) * 64 + l) * 8);
    float bQ0[2], bQ1[2];
#pragma unroll
    for (int ot = 0; ot < 2; ++ot) {
      bQ0[ot] = Wq_b[h0 * CDIM + os + ot * 16 + l15];
      bQ1[ot] = Wq_b[h1 * CDIM + os + ot * 16 + l15];
    }

    f32x4 accQ0[2][2], accQ1[2][2];
#pragma unroll
    for (int nt = 0; nt < 2; ++nt)
#pragma unroll
      for (int ot = 0; ot < 2; ++ot) { accQ0[nt][ot] = z4; accQ1[nt][ot] = z4; }
    __builtin_amdgcn_s_setprio(1);
#pragma unroll
    for (int kk = 0; kk < 4; ++kk)
#pragma unroll
      for (int ot = 0; ot < 2; ++ot)
#pragma unroll
        for (int nt = 0; nt < 2; ++nt) {
          accQ0[nt][ot] = mfma16(aq[nt][kk], wf0[ot][kk], accQ0[nt][ot]);
          accQ1[nt][ot] = mfma16(aq[nt][kk], wf1[ot][kk], accQ1[nt][ot]);
        }
    __builtin_amdgcn_s_setprio(0);

    bf16* ph0 = s_phi[pb][0];
    bf16* ph1 = s_phi[pb][1];
#pragma unroll
    for (int nt = 0; nt < 2; ++nt)
#pragma unroll
      for (int ot = 0; ot < 2; ++ot)
#pragma unroll
        for (int r = 0; r < 4; ++r) {
          const int ro = sidx(nt * 16 + lg * 4 + r, os + ot * 16 + l15);
          float x0 = fmaxf(accQ0[nt][ot][r] + bQ0[ot], 0.f) + 1e-6f;
          float x1 = fmaxf(accQ1[nt][ot][r] + bQ1[ot], 0.f) + 1e-6f;
          ph0[ro] = (bf16)(x0 * x0);
          ph1[ro] = (bf16)(x1 * x1);
        }
    __syncthreads();  // the ONLY barrier per pair

    bf16x8v kf1[2][4], kt1[4];
#pragma unroll
    for (int ot = 0; ot < 2; ++ot)
#pragma unroll
      for (int kk = 0; kk < 4; ++kk)
        kf1[ot][kk] = *(const bf16x8v*)(ktvT + tidx(h1, owt + ot, kk, l));
#pragma unroll
    for (int kk = 0; kk < 4; ++kk)
      kt1[kk] = *(const bf16x8v*)(ksb + ((h1 * 4 + kk) * 64 + l) * 8);

    {
      bf16x8v ap[2][4];
#pragma unroll
      for (int nt = 0; nt < 2; ++nt)
#pragma unroll
        for (int kk = 0; kk < 4; ++kk)
          ap[nt][kk] = *(const bf16x8v*)&ph0[sidx(nt * 16 + l15, kk * 32 + lg * 8)];
      f32x4 accN[2][2], accT[2];
#pragma unroll
      for (int nt = 0; nt < 2; ++nt) {
        accT[nt] = z4;
#pragma unroll
        for (int dt = 0; dt < 2; ++dt) accN[nt][dt] = z4;
      }
      __builtin_amdgcn_s_setprio(1);
#pragma unroll
      for (int kk = 0; kk < 4; ++kk) {
#pragma unroll
        for (int dt = 0; dt < 2; ++dt)
#pragma unroll
          for (int nt = 0; nt < 2; ++nt)
            accN[nt][dt] = mfma16(ap[nt][kk], kf0[dt][kk], accN[nt][dt]);
#pragma unroll
        for (int nt = 0; nt < 2; ++nt)
          accT[nt] = mfma16(ap[nt][kk], kt0[kk], accT[nt]);
      }
      __builtin_amdgcn_s_setprio(0);
#pragma unroll
      for (int nt = 0; nt < 2; ++nt)
#pragma unroll
        for (int r = 0; r < 4; ++r) {
          float tr = __shfl(accT[nt][r], l & 48);
          float m = 1.0f / tr;
#pragma unroll
          for (int dt = 0; dt < 2; ++dt)
            accO[nt][dt][r] = fmaf(accN[nt][dt][r], m, accO[nt][dt][r]);
        }
    }
    {
      bf16x8v ap[2][4];
#pragma unroll
      for (int nt = 0; nt < 2; ++nt)
#pragma unroll
        for (int kk = 0; kk < 4; ++kk)
          ap[nt][kk] = *(const bf16x8v*)&ph1[sidx(nt * 16 + l15, kk * 32 + lg * 8)];
      f32x4 accN[2][2], accT[2];
#pragma unroll
      for (int nt = 0; nt < 2; ++nt) {
        accT[nt] = z4;
#pragma unroll
        for (int dt = 0; dt < 2; ++dt) accN[nt][dt] = z4;
      }
      __builtin_amdgcn_s_setprio(1);
#pragma unroll
      for (int kk = 0; kk < 4; ++kk) {
#pragma unroll
        for (int dt = 0; dt < 2; ++dt)
#pragma unroll
          for (int nt = 0; nt < 2; ++nt)
            accN[nt][dt] = mfma16(ap[nt][kk], kf1[dt][kk], accN[nt][dt]);
#pragma unroll
        for (int nt = 0; nt < 2; ++nt)
          accT[nt] = mfma16(ap[nt][kk], kt1[kk], accT[nt]);
      }
      __builtin_amdgcn_s_setprio(0);
#pragma unroll
      for (int nt = 0; nt < 2; ++nt)
#pragma unroll
        for (int r = 0; r < 4; ++r) {
          float tr = __shfl(accT[nt][r], l & 48);
          float m = 1.0f / tr;
#pragma unroll
          for (int dt = 0; dt < 2; ++dt)
            accO[nt][dt][r] = fmaf(accN[nt][dt][r], m, accO[nt][dt][r]);
        }
    }
  }

  // fused vss GEMM: A-frags from srcT
  const int rb0 = blockIdx.x * 2;
#pragma unroll
  for (int kk = 0; kk < 4; ++kk) {
    bf16x8v a[2];
#pragma unroll
    for (int nt = 0; nt < 2; ++nt)
      a[nt] = *(const bf16x8v*)(srcT + (((rb0 + nt) * 4 + kk) * 64 + l) * 8);
#pragma unroll
    for (int ot = 0; ot < 2; ++ot) {
      bf16x8v bw = *(const bf16x8v*)(w2sT + tidx(0, owt + ot, kk, l));
#pragma unroll
      for (int nt = 0; nt < 2; ++nt)
        accO[nt][ot] = mfma16(a[nt], bw, accO[nt][ot]);
    }
  }
  float bb[2];
#pragma unroll
  for (int ot = 0; ot < 2; ++ot) bb[ot] = b2s[os + ot * 16 + l15];

  float ps[2][4];
#pragma unroll
  for (int nt = 0; nt < 2; ++nt)
#pragma unroll
    for (int r = 0; r < 4; ++r) ps[nt][r] = 0.f;
#pragma unroll
  for (int nt = 0; nt < 2; ++nt)
#pragma unroll
    for (int ot = 0; ot < 2; ++ot)
#pragma unroll
      for (int r = 0; r < 4; ++r) {
        float v = (accO[nt][ot][r] + bb[ot]) * 0.125f;
        accO[nt][ot][r] = v;
        ps[nt][r] += v * v;
      }
#pragma unroll
  for (int nt = 0; nt < 2; ++nt)
#pragma unroll
    for (int r = 0; r < 4; ++r) {
      float t = xred16d(ps[nt][r]);
      if (l15 == 0) s_time[w][nt * 16 + lg * 4 + r] = t;
    }
#pragma unroll
  for (int nt = 0; nt < 2; ++nt)
#pragma unroll
    for (int ot = 0; ot < 2; ++ot)
#pragma unroll
      for (int r = 0; r < 4; ++r)
        out[(nb + nt * 16 + lg * 4 + r) * 129 + 1 + os + ot * 16 + l15] = accO[nt][ot][r];
  __syncthreads();
  if (tid < QT) {
    float S = 1.0f + s_time[0][tid] + s_time[1][tid] + s_time[2][tid] + s_time[3][tid];
    out[(nb + tid) * 129] = sqrtf(S);
  }
}

// ---------------------------------------------------------------------------
extern "C" void kernel_launch(void* const* d_in, const int* in_sizes, int n_in,
                              void* d_out, int out_size, void* d_ws, size_t ws_size,
                              hipStream_t stream) {
  const float* query  = (const float*)d_in[0];
  const float* source = (const float*)d_in[1];
  const float* Wq_w   = (const float*)d_in[2];
  const float* Wq_b   = (const float*)d_in[3];
  const float* Wk_w   = (const float*)d_in[4];
  const float* Wk_b   = (const float*)d_in[5];
  const float* Wv_w   = (const float*)d_in[6];
  const float* Wv_b   = (const float*)d_in[7];
  const float* vmw    = (const float*)d_in[8];
  const float* vmb    = (const float*)d_in[9];

  char* ws = (char*)d_ws;
  bf16*  wqT       = (bf16*)(ws + 0);           // 262144
  bf16*  wkT       = (bf16*)(ws + 262144);      // 262144
  bf16*  wvT       = (bf16*)(ws + 524288);      // 262144
  bf16*  w2sT      = (bf16*)(ws + 786432);      // 32768
  float* b2s       = (float*)(ws + 819200);     // 512
  float* Wvs       = (float*)(ws + 819712);     // 65536
  float* Wvbs      = (float*)(ws + 885248);     // 512
  bf16*  ktvT      = (bf16*)(ws + 885760);      // 262144
  bf16*  ksb       = (bf16*)(ws + 1147904);     // 32768
  bf16*  srcT      = (bf16*)(ws + 1180672);     // 8388608
  float* ksum_part = (float*)(ws + 9569280);    // 262144
  bf16*  ktv_part  = (bf16*)(ws + 10093568);    // 64*262144 = 16.78 MB

  int nchunk = 64, nsub = 8;
  if (ws_size < 10093568ull + 64ull * 262144ull) { nchunk = 32; nsub = 16; }

  k_prepA<<<2560, 256, 0, stream>>>(source, Wq_w, Wk_w, Wv_w, Wv_b,
                                    srcT, wqT, wkT, wvT, Wvs, Wvbs);
  k_ktv<<<nchunk * NH, 256, 0, stream>>>(srcT, wkT, wvT, Wk_b, Wv_b,
                                         ktv_part, ksum_part, nsub, nchunk / 8);
  k_finishB<<<640, 256, 0, stream>>>(ktv_part, ksum_part, vmw, vmb, Wvs, Wvbs,
                                     ktvT, ksb, w2sT, b2s, nchunk);
  k_out<<<NTOK / QT, 256, 0, stream>>>(query, srcT, wqT, Wq_b, ktvT, ksb,
                                       w2sT, b2s, (float*)d_out);
}